// Round 4
// baseline (178.792 us; speedup 1.0000x reference)
//
#include <hip/hip_runtime.h>

// URGCN layer, MI355X — round 4.
// Algebra: msg_agg = (Σ_e T[src] + u[rel]) / deg with T = h@Wn (bf16, MFMA),
//          u = rel@Wn.  out = S' + msg_agg where S' = h + h@Wself (f32, in d_out).
// Pipeline: wconv -> hist -> scan{3} -> fill -> transform(MFMA) -> gather.

constexpr int NNODES = 50000;
constexpr int NEDGES = 600000;
constexpr int NRELS  = 500;
constexpr int DIM    = 128;

constexpr int SCB = 256;
constexpr int NSB = (NNODES + SCB - 1) / SCB;   // 196

constexpr int NODE_BLKS = (NNODES + 63) / 64;   // 782
constexpr int REL_BLKS  = (NRELS  + 63) / 64;   // 8

// ---------------- workspace layout (bytes), total ~16.1 MB ----------------
constexpr size_t OFF_CNT_B = 0;                            // int[50000]
constexpr size_t OFF_OFF_B = 204800;                       // int[50001]
constexpr size_t OFF_CUR_B = 409600;                       // int[50000]
constexpr size_t OFF_BSM_B = 614400;                       // int[NSB]
constexpr size_t OFF_BBS_B = 618496;                       // int[256]
constexpr size_t OFF_BKT_B = 622592;                       // uint[600000]
constexpr size_t OFF_BTN_B = OFF_BKT_B + 2400000;          // ushort[128*128] Wn^T bf16
constexpr size_t OFF_BTS_B = OFF_BTN_B + 32768;            // ushort[128*128] Ws^T bf16
constexpr size_t OFF_T_B   = OFF_BTS_B + 32768;            // ushort[50000*128]
constexpr size_t OFF_U_B   = OFF_T_B + (size_t)NNODES * DIM * 2; // ushort[500*128]

typedef short s8f __attribute__((ext_vector_type(8)));   // 8 bf16 (4 VGPR)
typedef float f4  __attribute__((ext_vector_type(4)));   // MFMA acc

static __device__ __forceinline__ unsigned short f2bf(float f) {
    unsigned u = __builtin_bit_cast(unsigned, f);
    u += 0x7FFFu + ((u >> 16) & 1u);        // round-to-nearest-even
    return (unsigned short)(u >> 16);
}
static __device__ __forceinline__ float bflo(unsigned v) {
    return __builtin_bit_cast(float, v << 16);
}
static __device__ __forceinline__ float bfhi(unsigned v) {
    return __builtin_bit_cast(float, v & 0xFFFF0000u);
}

// ---------------------------------------------------------------------------
__global__ __launch_bounds__(256) void wconv(const float* __restrict__ wn,
                                             const float* __restrict__ wsf,
                                             unsigned short* __restrict__ btn,
                                             unsigned short* __restrict__ bts)
{
    for (int idx = threadIdx.x; idx < DIM * DIM; idx += 256) {
        int k = idx >> 7, j = idx & 127;
        btn[(size_t)j * DIM + k] = f2bf(wn[idx]);    // [col][k] bf16
        bts[(size_t)j * DIM + k] = f2bf(wsf[idx]);
    }
}

__global__ __launch_bounds__(256) void hist(const int* __restrict__ edges,
                                            int* __restrict__ cnt)
{
    int e = blockIdx.x * 256 + threadIdx.x;
    if (e >= NEDGES) return;
    atomicAdd(cnt + edges[e * 3 + 2], 1);
}

__global__ __launch_bounds__(SCB) void scan_partial(const int* __restrict__ cnt,
                                                    int* __restrict__ bsum)
{
    int gid = blockIdx.x * SCB + threadIdx.x;
    int v = (gid < NNODES) ? cnt[gid] : 0;
    #pragma unroll
    for (int d = 32; d > 0; d >>= 1) v += __shfl_down(v, d, 64);
    __shared__ int ws[SCB / 64];
    if ((threadIdx.x & 63) == 0) ws[threadIdx.x >> 6] = v;
    __syncthreads();
    if (threadIdx.x == 0) {
        int s = 0;
        #pragma unroll
        for (int w = 0; w < SCB / 64; ++w) s += ws[w];
        bsum[blockIdx.x] = s;
    }
}

__global__ __launch_bounds__(256) void scan_bsum(const int* __restrict__ bsum,
                                                 int* __restrict__ bbase,
                                                 int* __restrict__ off)
{
    __shared__ int sh[256];
    int t = threadIdx.x;
    sh[t] = (t < NSB) ? bsum[t] : 0;
    __syncthreads();
    #pragma unroll
    for (int d = 1; d < 256; d <<= 1) {
        int u = (t >= d) ? sh[t - d] : 0;
        __syncthreads();
        sh[t] += u;
        __syncthreads();
    }
    bbase[t] = (t == 0) ? 0 : sh[t - 1];
    if (t == 255) off[NNODES] = sh[255];
}

__global__ __launch_bounds__(SCB) void scan_final(const int* __restrict__ cnt,
                                                  const int* __restrict__ bbase,
                                                  int* __restrict__ off,
                                                  int* __restrict__ cursor)
{
    __shared__ int sh[SCB];
    int t = threadIdx.x;
    int gid = blockIdx.x * SCB + t;
    sh[t] = (gid < NNODES) ? cnt[gid] : 0;
    __syncthreads();
    #pragma unroll
    for (int d = 1; d < SCB; d <<= 1) {
        int u = (t >= d) ? sh[t - d] : 0;
        __syncthreads();
        sh[t] += u;
        __syncthreads();
    }
    if (gid < NNODES) {
        int excl = bbase[blockIdx.x] + ((t == 0) ? 0 : sh[t - 1]);
        off[gid] = excl;
        cursor[gid] = excl;
    }
}

__global__ __launch_bounds__(256) void fill(const int* __restrict__ edges,
                                            int* __restrict__ cursor,
                                            unsigned* __restrict__ buckets)
{
    int e = blockIdx.x * 256 + threadIdx.x;
    if (e >= NEDGES) return;
    int src = edges[e * 3 + 0];
    int rel = edges[e * 3 + 1];
    int dst = edges[e * 3 + 2];
    int pos = atomicAdd(cursor + dst, 1);
    buckets[pos] = (unsigned)src | ((unsigned)rel << 16);
}

// ---------------------------------------------------------------------------
// transform: per 64-row block (4 waves x 16 rows), MFMA 16x16x32 bf16.
//  node blocks: T = A@Wn (bf16 -> ws), S' = h + A@Wself (f32 -> d_out)
//  rel blocks : U = A@Wn (bf16 -> ws)
// Fragment maps (m89-verified family): A: row=lane&15, k=8*(lane>>4)+reg;
// B (staged [col][k]): col=lane&15, k=8*(lane>>4)+reg; D: col=lane&15,
// row=4*(lane>>4)+reg.
// ---------------------------------------------------------------------------
__global__ __launch_bounds__(256) void transform(
    const float* __restrict__ nodes, const float* __restrict__ rels,
    const unsigned short* __restrict__ btn, const unsigned short* __restrict__ bts,
    unsigned short* __restrict__ T, unsigned short* __restrict__ U,
    float* __restrict__ Sp)
{
    int blk = blockIdx.x;
    bool isRel = blk >= NODE_BLKS;
    const float* A = isRel ? rels : nodes;
    int nrows = isRel ? NRELS : NNODES;
    int rowbase = (isRel ? (blk - NODE_BLKS) : blk) * 64;

    int wv = threadIdx.x >> 6;
    int l  = threadIdx.x & 63;
    int r0 = rowbase + wv * 16;
    int arow  = r0 + (l & 15);
    int arowc = arow < nrows ? arow : nrows - 1;
    int kg = l >> 4;

    s8f afrag[4];
    #pragma unroll
    for (int ks = 0; ks < 4; ++ks) {
        const float* p = A + (size_t)arowc * DIM + ks * 32 + kg * 8;
        float4 x = *(const float4*)p;
        float4 y = *(const float4*)(p + 4);
        s8f a;
        a[0] = (short)f2bf(x.x); a[1] = (short)f2bf(x.y);
        a[2] = (short)f2bf(x.z); a[3] = (short)f2bf(x.w);
        a[4] = (short)f2bf(y.x); a[5] = (short)f2bf(y.y);
        a[6] = (short)f2bf(y.z); a[7] = (short)f2bf(y.w);
        afrag[ks] = a;
    }

    #pragma unroll 2
    for (int ct = 0; ct < 8; ++ct) {
        int col = ct * 16 + (l & 15);
        const unsigned short* bnp = btn + (size_t)col * DIM + kg * 8;
        if (!isRel) {
            const unsigned short* bsp = bts + (size_t)col * DIM + kg * 8;
            f4 accN = {0.f, 0.f, 0.f, 0.f};
            f4 accS = {0.f, 0.f, 0.f, 0.f};
            #pragma unroll
            for (int ks = 0; ks < 4; ++ks) {
                s8f bn = *(const s8f*)(bnp + ks * 32);
                s8f bs = *(const s8f*)(bsp + ks * 32);
                accN = __builtin_amdgcn_mfma_f32_16x16x32_bf16(afrag[ks], bn, accN, 0, 0, 0);
                accS = __builtin_amdgcn_mfma_f32_16x16x32_bf16(afrag[ks], bs, accS, 0, 0, 0);
            }
            #pragma unroll
            for (int r = 0; r < 4; ++r) {
                int grow = r0 + kg * 4 + r;
                if (grow < nrows) {
                    size_t idx = (size_t)grow * DIM + col;
                    T[idx]  = f2bf(accN[r]);
                    Sp[idx] = nodes[idx] + accS[r];
                }
            }
        } else {
            f4 accN = {0.f, 0.f, 0.f, 0.f};
            #pragma unroll
            for (int ks = 0; ks < 4; ++ks) {
                s8f bn = *(const s8f*)(bnp + ks * 32);
                accN = __builtin_amdgcn_mfma_f32_16x16x32_bf16(afrag[ks], bn, accN, 0, 0, 0);
            }
            #pragma unroll
            for (int r = 0; r < 4; ++r) {
                int grow = r0 + kg * 4 + r;
                if (grow < nrows)
                    U[(size_t)grow * DIM + col] = f2bf(accN[r]);
            }
        }
    }
}

// ---------------------------------------------------------------------------
// gather: full wave per node; halves walk alternate bucket entries; lane
// (l&31) covers 4 bf16 columns (8B). out = S'[n] + acc/deg (in-place d_out).
// ---------------------------------------------------------------------------
__global__ __launch_bounds__(256) void gather(
    const unsigned short* __restrict__ T, const unsigned short* __restrict__ U,
    const int* __restrict__ off, const unsigned* __restrict__ buckets,
    const float* __restrict__ nodes, const float* __restrict__ wse,
    float* __restrict__ outp)
{
    int tid = blockIdx.x * 256 + threadIdx.x;
    int n = tid >> 6;
    if (n >= NNODES) return;
    int l = threadIdx.x & 63;
    int half = l >> 5;
    int c = l & 31;

    int beg = off[n];
    int end = off[n + 1];

    if (beg == end) {
        // rare (~e^-12 per node): out = h + h @ Wse, straight f32 matvec
        if (half == 0) {
            float s0 = 0, s1 = 0, s2 = 0, s3 = 0;
            for (int k = 0; k < DIM; ++k) {
                float hk = nodes[(size_t)n * DIM + k];
                const float* wr = wse + (size_t)k * DIM + c * 4;
                s0 += hk * wr[0]; s1 += hk * wr[1];
                s2 += hk * wr[2]; s3 += hk * wr[3];
            }
            float4 hv = *(const float4*)(nodes + (size_t)n * DIM + c * 4);
            float4 o = { hv.x + s0, hv.y + s1, hv.z + s2, hv.w + s3 };
            *(float4*)(outp + (size_t)n * DIM + c * 4) = o;
        }
        return;
    }

    float4 acc = make_float4(0.f, 0.f, 0.f, 0.f);
    int i = beg + half;
    for (; i + 2 < end; i += 4) {
        unsigned b0 = buckets[i];
        unsigned b1 = buckets[i + 2];
        uint2 t0 = *(const uint2*)(T + (size_t)(b0 & 0xFFFFu) * DIM + c * 4);
        uint2 u0 = *(const uint2*)(U + (size_t)(b0 >> 16)     * DIM + c * 4);
        uint2 t1 = *(const uint2*)(T + (size_t)(b1 & 0xFFFFu) * DIM + c * 4);
        uint2 u1 = *(const uint2*)(U + (size_t)(b1 >> 16)     * DIM + c * 4);
        acc.x += bflo(t0.x) + bflo(u0.x); acc.y += bfhi(t0.x) + bfhi(u0.x);
        acc.z += bflo(t0.y) + bflo(u0.y); acc.w += bfhi(t0.y) + bfhi(u0.y);
        acc.x += bflo(t1.x) + bflo(u1.x); acc.y += bfhi(t1.x) + bfhi(u1.x);
        acc.z += bflo(t1.y) + bflo(u1.y); acc.w += bfhi(t1.y) + bfhi(u1.y);
    }
    if (i < end) {
        unsigned b0 = buckets[i];
        uint2 t0 = *(const uint2*)(T + (size_t)(b0 & 0xFFFFu) * DIM + c * 4);
        uint2 u0 = *(const uint2*)(U + (size_t)(b0 >> 16)     * DIM + c * 4);
        acc.x += bflo(t0.x) + bflo(u0.x); acc.y += bfhi(t0.x) + bfhi(u0.x);
        acc.z += bflo(t0.y) + bflo(u0.y); acc.w += bfhi(t0.y) + bfhi(u0.y);
    }

    acc.x += __shfl_xor(acc.x, 32, 64);
    acc.y += __shfl_xor(acc.y, 32, 64);
    acc.z += __shfl_xor(acc.z, 32, 64);
    acc.w += __shfl_xor(acc.w, 32, 64);

    if (half == 0) {
        float inv = 1.0f / (float)(end - beg);
        float4 sp = *(const float4*)(outp + (size_t)n * DIM + c * 4);
        float4 o = { sp.x + acc.x * inv, sp.y + acc.y * inv,
                     sp.z + acc.z * inv, sp.w + acc.w * inv };
        *(float4*)(outp + (size_t)n * DIM + c * 4) = o;
    }
}

// ---------------------------------------------------------------------------
extern "C" void kernel_launch(void* const* d_in, const int* in_sizes, int n_in,
                              void* d_out, int out_size, void* d_ws, size_t ws_size,
                              hipStream_t stream)
{
    const float* nodes = (const float*)d_in[0];
    const float* rels  = (const float*)d_in[1];
    const int*   edges = (const int*)d_in[2];
    const float* wn    = (const float*)d_in[3];
    const float* wsf   = (const float*)d_in[4];
    const float* wse   = (const float*)d_in[5];
    float* out = (float*)d_out;

    char* ws = (char*)d_ws;
    int*            cnt     = (int*)(ws + OFF_CNT_B);
    int*            off     = (int*)(ws + OFF_OFF_B);
    int*            cursor  = (int*)(ws + OFF_CUR_B);
    int*            bsum    = (int*)(ws + OFF_BSM_B);
    int*            bbase   = (int*)(ws + OFF_BBS_B);
    unsigned*       buckets = (unsigned*)(ws + OFF_BKT_B);
    unsigned short* btn     = (unsigned short*)(ws + OFF_BTN_B);
    unsigned short* bts     = (unsigned short*)(ws + OFF_BTS_B);
    unsigned short* T       = (unsigned short*)(ws + OFF_T_B);
    unsigned short* U       = (unsigned short*)(ws + OFF_U_B);

    hipMemsetAsync(cnt, 0, (size_t)NNODES * sizeof(int), stream);
    wconv<<<1, 256, 0, stream>>>(wn, wsf, btn, bts);

    int eb = (NEDGES + 255) / 256;
    hist<<<eb, 256, 0, stream>>>(edges, cnt);
    scan_partial<<<NSB, SCB, 0, stream>>>(cnt, bsum);
    scan_bsum<<<1, 256, 0, stream>>>(bsum, bbase, off);
    scan_final<<<NSB, SCB, 0, stream>>>(cnt, bbase, off, cursor);
    fill<<<eb, 256, 0, stream>>>(edges, cursor, buckets);

    transform<<<NODE_BLKS + REL_BLKS, 256, 0, stream>>>(nodes, rels, btn, bts, T, U, out);

    int gb = (NNODES * 64 + 255) / 256;
    gather<<<gb, 256, 0, stream>>>(T, U, off, buckets, nodes, wse, out);
}

// Round 5
// 158.017 us; speedup vs baseline: 1.1315x; 1.1315x over previous
//
#include <hip/hip_runtime.h>

// URGCN layer, MI355X — round 5.
// r4 post-mortem: wconv was 1 block (49us!), transform writes were 32B-granule
// scattered (58.7MB vs 38.4 ideal). Fix: parallel wconv + LDS-transpose
// epilogue in transform for fully coalesced T/Sp stores.
//
// Algebra: msg_agg = (Σ_e T[src] + u[rel]) / deg with T = h@Wn (bf16, MFMA),
//          u = rel@Wn.  out = S' + msg_agg where S' = h + h@Wself (f32, d_out).

constexpr int NNODES = 50000;
constexpr int NEDGES = 600000;
constexpr int NRELS  = 500;
constexpr int DIM    = 128;

constexpr int SCB = 256;
constexpr int NSB = (NNODES + SCB - 1) / SCB;   // 196

constexpr int NODE_BLKS = (NNODES + 63) / 64;   // 782
constexpr int REL_BLKS  = (NRELS  + 63) / 64;   // 8

constexpr int TPAD = 8;   // shorts pad for T LDS tile (keeps 16B row align)
constexpr int SPAD = 4;   // floats pad for S LDS tile

// ---------------- workspace layout (bytes), total ~16.1 MB ----------------
constexpr size_t OFF_CNT_B = 0;                            // int[50000]
constexpr size_t OFF_OFF_B = 204800;                       // int[50001]
constexpr size_t OFF_CUR_B = 409600;                       // int[50000]
constexpr size_t OFF_BSM_B = 614400;                       // int[NSB]
constexpr size_t OFF_BBS_B = 618496;                       // int[256]
constexpr size_t OFF_BKT_B = 622592;                       // uint[600000]
constexpr size_t OFF_BTN_B = OFF_BKT_B + 2400000;          // ushort[128*128] Wn^T bf16
constexpr size_t OFF_BTS_B = OFF_BTN_B + 32768;            // ushort[128*128] Ws^T bf16
constexpr size_t OFF_T_B   = OFF_BTS_B + 32768;            // ushort[50000*128]
constexpr size_t OFF_U_B   = OFF_T_B + (size_t)NNODES * DIM * 2; // ushort[500*128]

typedef short s8f __attribute__((ext_vector_type(8)));   // 8 bf16 (4 VGPR)
typedef float f4  __attribute__((ext_vector_type(4)));   // MFMA acc

static __device__ __forceinline__ unsigned short f2bf(float f) {
    unsigned u = __builtin_bit_cast(unsigned, f);
    u += 0x7FFFu + ((u >> 16) & 1u);        // round-to-nearest-even
    return (unsigned short)(u >> 16);
}
static __device__ __forceinline__ float bflo(unsigned v) {
    return __builtin_bit_cast(float, v << 16);
}
static __device__ __forceinline__ float bfhi(unsigned v) {
    return __builtin_bit_cast(float, v & 0xFFFF0000u);
}

// ---------------------------------------------------------------------------
__global__ __launch_bounds__(256) void wconv(const float* __restrict__ wn,
                                             const float* __restrict__ wsf,
                                             unsigned short* __restrict__ btn,
                                             unsigned short* __restrict__ bts)
{
    int idx = blockIdx.x * 256 + threadIdx.x;
    if (idx >= DIM * DIM) return;
    int k = idx >> 7, j = idx & 127;
    btn[(size_t)j * DIM + k] = f2bf(wn[idx]);    // [col][k] bf16
    bts[(size_t)j * DIM + k] = f2bf(wsf[idx]);
}

__global__ __launch_bounds__(256) void hist(const int* __restrict__ edges,
                                            int* __restrict__ cnt)
{
    int e = blockIdx.x * 256 + threadIdx.x;
    if (e >= NEDGES) return;
    atomicAdd(cnt + edges[e * 3 + 2], 1);
}

__global__ __launch_bounds__(SCB) void scan_partial(const int* __restrict__ cnt,
                                                    int* __restrict__ bsum)
{
    int gid = blockIdx.x * SCB + threadIdx.x;
    int v = (gid < NNODES) ? cnt[gid] : 0;
    #pragma unroll
    for (int d = 32; d > 0; d >>= 1) v += __shfl_down(v, d, 64);
    __shared__ int ws[SCB / 64];
    if ((threadIdx.x & 63) == 0) ws[threadIdx.x >> 6] = v;
    __syncthreads();
    if (threadIdx.x == 0) {
        int s = 0;
        #pragma unroll
        for (int w = 0; w < SCB / 64; ++w) s += ws[w];
        bsum[blockIdx.x] = s;
    }
}

__global__ __launch_bounds__(256) void scan_bsum(const int* __restrict__ bsum,
                                                 int* __restrict__ bbase,
                                                 int* __restrict__ off)
{
    __shared__ int sh[256];
    int t = threadIdx.x;
    sh[t] = (t < NSB) ? bsum[t] : 0;
    __syncthreads();
    #pragma unroll
    for (int d = 1; d < 256; d <<= 1) {
        int u = (t >= d) ? sh[t - d] : 0;
        __syncthreads();
        sh[t] += u;
        __syncthreads();
    }
    bbase[t] = (t == 0) ? 0 : sh[t - 1];
    if (t == 255) off[NNODES] = sh[255];
}

__global__ __launch_bounds__(SCB) void scan_final(const int* __restrict__ cnt,
                                                  const int* __restrict__ bbase,
                                                  int* __restrict__ off,
                                                  int* __restrict__ cursor)
{
    __shared__ int sh[SCB];
    int t = threadIdx.x;
    int gid = blockIdx.x * SCB + t;
    sh[t] = (gid < NNODES) ? cnt[gid] : 0;
    __syncthreads();
    #pragma unroll
    for (int d = 1; d < SCB; d <<= 1) {
        int u = (t >= d) ? sh[t - d] : 0;
        __syncthreads();
        sh[t] += u;
        __syncthreads();
    }
    if (gid < NNODES) {
        int excl = bbase[blockIdx.x] + ((t == 0) ? 0 : sh[t - 1]);
        off[gid] = excl;
        cursor[gid] = excl;
    }
}

__global__ __launch_bounds__(256) void fill(const int* __restrict__ edges,
                                            int* __restrict__ cursor,
                                            unsigned* __restrict__ buckets)
{
    int e = blockIdx.x * 256 + threadIdx.x;
    if (e >= NEDGES) return;
    int src = edges[e * 3 + 0];
    int rel = edges[e * 3 + 1];
    int dst = edges[e * 3 + 2];
    int pos = atomicAdd(cursor + dst, 1);
    buckets[pos] = (unsigned)src | ((unsigned)rel << 16);
}

// ---------------------------------------------------------------------------
// transform: per 64-row block (4 waves x 16 rows), MFMA 16x16x32 bf16.
//  node blocks: T = A@Wn (bf16 -> ws), S' = h + A@Wself (f32 -> d_out)
//  rel blocks : U = A@Wn (bf16 -> ws)
// Epilogue stages tiles in LDS then stores full contiguous rows (256B/512B
// segments) — fixes r4's 32B-granule scattered stores.
// ---------------------------------------------------------------------------
__global__ __launch_bounds__(256) void transform(
    const float* __restrict__ nodes, const float* __restrict__ rels,
    const unsigned short* __restrict__ btn, const unsigned short* __restrict__ bts,
    unsigned short* __restrict__ T, unsigned short* __restrict__ U,
    float* __restrict__ Sp)
{
    __shared__ __align__(16) unsigned short ldsT[4][16][DIM + TPAD]; // 17.4 KB
    __shared__ __align__(16) float          ldsS[4][16][DIM + SPAD]; // 33.8 KB

    int blk = blockIdx.x;
    bool isRel = blk >= NODE_BLKS;
    const float* A = isRel ? rels : nodes;
    int nrows = isRel ? NRELS : NNODES;
    int rowbase = (isRel ? (blk - NODE_BLKS) : blk) * 64;

    int wv = threadIdx.x >> 6;
    int l  = threadIdx.x & 63;
    int r0 = rowbase + wv * 16;
    int m  = l & 15;
    int kg = l >> 4;
    int arow  = r0 + m;
    int arowc = arow < nrows ? arow : nrows - 1;

    s8f afrag[4];
    #pragma unroll
    for (int ks = 0; ks < 4; ++ks) {
        const float* p = A + (size_t)arowc * DIM + ks * 32 + kg * 8;
        float4 x = *(const float4*)p;
        float4 y = *(const float4*)(p + 4);
        s8f a;
        a[0] = (short)f2bf(x.x); a[1] = (short)f2bf(x.y);
        a[2] = (short)f2bf(x.z); a[3] = (short)f2bf(x.w);
        a[4] = (short)f2bf(y.x); a[5] = (short)f2bf(y.y);
        a[6] = (short)f2bf(y.z); a[7] = (short)f2bf(y.w);
        afrag[ks] = a;
    }

    #pragma unroll 2
    for (int ct = 0; ct < 8; ++ct) {
        int col = ct * 16 + m;
        const unsigned short* bnp = btn + (size_t)col * DIM + kg * 8;
        f4 accN = {0.f, 0.f, 0.f, 0.f};
        #pragma unroll
        for (int ks = 0; ks < 4; ++ks)
            accN = __builtin_amdgcn_mfma_f32_16x16x32_bf16(afrag[ks], *(const s8f*)(bnp + ks * 32), accN, 0, 0, 0);
        #pragma unroll
        for (int r = 0; r < 4; ++r)
            ldsT[wv][kg * 4 + r][col] = f2bf(accN[r]);

        if (!isRel) {
            const unsigned short* bsp = bts + (size_t)col * DIM + kg * 8;
            f4 accS = {0.f, 0.f, 0.f, 0.f};
            #pragma unroll
            for (int ks = 0; ks < 4; ++ks)
                accS = __builtin_amdgcn_mfma_f32_16x16x32_bf16(afrag[ks], *(const s8f*)(bsp + ks * 32), accS, 0, 0, 0);
            #pragma unroll
            for (int r = 0; r < 4; ++r)
                ldsS[wv][kg * 4 + r][col] = accS[r];
        }
    }
    __syncthreads();

    // epilogue: coalesced stores — each pass writes 4 full rows
    unsigned short* Tout = isRel ? U : T;
    #pragma unroll
    for (int p = 0; p < 4; ++p) {
        int row = p * 4 + kg;
        int rg  = r0 + row;
        if (rg < nrows)
            *(uint4*)(Tout + (size_t)rg * DIM + m * 8) =
                *(const uint4*)&ldsT[wv][row][m * 8];
    }
    if (!isRel) {
        #pragma unroll
        for (int p = 0; p < 4; ++p) {
            int row = p * 4 + kg;
            int rg  = r0 + row;
            if (rg < nrows) {
                const float* nrow = nodes + (size_t)rg * DIM;
                float* orow = Sp + (size_t)rg * DIM;
                #pragma unroll
                for (int j = 0; j < 2; ++j) {
                    int c0 = m * 4 + j * 64;
                    float4 s = *(const float4*)&ldsS[wv][row][c0];
                    float4 h = *(const float4*)(nrow + c0);
                    float4 o = { h.x + s.x, h.y + s.y, h.z + s.z, h.w + s.w };
                    *(float4*)(orow + c0) = o;
                }
            }
        }
    }
}

// ---------------------------------------------------------------------------
// gather: full wave per node; halves walk alternate bucket entries; lane
// (l&31) covers 4 bf16 columns (8B). out = S'[n] + acc/deg (in-place d_out).
// ---------------------------------------------------------------------------
__global__ __launch_bounds__(256) void gather(
    const unsigned short* __restrict__ T, const unsigned short* __restrict__ U,
    const int* __restrict__ off, const unsigned* __restrict__ buckets,
    const float* __restrict__ nodes, const float* __restrict__ wse,
    float* __restrict__ outp)
{
    int tid = blockIdx.x * 256 + threadIdx.x;
    int n = tid >> 6;
    if (n >= NNODES) return;
    int l = threadIdx.x & 63;
    int half = l >> 5;
    int c = l & 31;

    int beg = off[n];
    int end = off[n + 1];

    if (beg == end) {
        // rare (~e^-12 per node): out = h + h @ Wse, straight f32 matvec
        if (half == 0) {
            float s0 = 0, s1 = 0, s2 = 0, s3 = 0;
            for (int k = 0; k < DIM; ++k) {
                float hk = nodes[(size_t)n * DIM + k];
                const float* wr = wse + (size_t)k * DIM + c * 4;
                s0 += hk * wr[0]; s1 += hk * wr[1];
                s2 += hk * wr[2]; s3 += hk * wr[3];
            }
            float4 hv = *(const float4*)(nodes + (size_t)n * DIM + c * 4);
            float4 o = { hv.x + s0, hv.y + s1, hv.z + s2, hv.w + s3 };
            *(float4*)(outp + (size_t)n * DIM + c * 4) = o;
        }
        return;
    }

    float4 acc = make_float4(0.f, 0.f, 0.f, 0.f);
    int i = beg + half;
    for (; i + 2 < end; i += 4) {
        unsigned b0 = buckets[i];
        unsigned b1 = buckets[i + 2];
        uint2 t0 = *(const uint2*)(T + (size_t)(b0 & 0xFFFFu) * DIM + c * 4);
        uint2 u0 = *(const uint2*)(U + (size_t)(b0 >> 16)     * DIM + c * 4);
        uint2 t1 = *(const uint2*)(T + (size_t)(b1 & 0xFFFFu) * DIM + c * 4);
        uint2 u1 = *(const uint2*)(U + (size_t)(b1 >> 16)     * DIM + c * 4);
        acc.x += bflo(t0.x) + bflo(u0.x); acc.y += bfhi(t0.x) + bfhi(u0.x);
        acc.z += bflo(t0.y) + bflo(u0.y); acc.w += bfhi(t0.y) + bfhi(u0.y);
        acc.x += bflo(t1.x) + bflo(u1.x); acc.y += bfhi(t1.x) + bfhi(u1.x);
        acc.z += bflo(t1.y) + bflo(u1.y); acc.w += bfhi(t1.y) + bfhi(u1.y);
    }
    if (i < end) {
        unsigned b0 = buckets[i];
        uint2 t0 = *(const uint2*)(T + (size_t)(b0 & 0xFFFFu) * DIM + c * 4);
        uint2 u0 = *(const uint2*)(U + (size_t)(b0 >> 16)     * DIM + c * 4);
        acc.x += bflo(t0.x) + bflo(u0.x); acc.y += bfhi(t0.x) + bfhi(u0.x);
        acc.z += bflo(t0.y) + bflo(u0.y); acc.w += bfhi(t0.y) + bfhi(u0.y);
    }

    acc.x += __shfl_xor(acc.x, 32, 64);
    acc.y += __shfl_xor(acc.y, 32, 64);
    acc.z += __shfl_xor(acc.z, 32, 64);
    acc.w += __shfl_xor(acc.w, 32, 64);

    if (half == 0) {
        float inv = 1.0f / (float)(end - beg);
        float4 sp = *(const float4*)(outp + (size_t)n * DIM + c * 4);
        float4 o = { sp.x + acc.x * inv, sp.y + acc.y * inv,
                     sp.z + acc.z * inv, sp.w + acc.w * inv };
        *(float4*)(outp + (size_t)n * DIM + c * 4) = o;
    }
}

// ---------------------------------------------------------------------------
extern "C" void kernel_launch(void* const* d_in, const int* in_sizes, int n_in,
                              void* d_out, int out_size, void* d_ws, size_t ws_size,
                              hipStream_t stream)
{
    const float* nodes = (const float*)d_in[0];
    const float* rels  = (const float*)d_in[1];
    const int*   edges = (const int*)d_in[2];
    const float* wn    = (const float*)d_in[3];
    const float* wsf   = (const float*)d_in[4];
    const float* wse   = (const float*)d_in[5];
    float* out = (float*)d_out;

    char* ws = (char*)d_ws;
    int*            cnt     = (int*)(ws + OFF_CNT_B);
    int*            off     = (int*)(ws + OFF_OFF_B);
    int*            cursor  = (int*)(ws + OFF_CUR_B);
    int*            bsum    = (int*)(ws + OFF_BSM_B);
    int*            bbase   = (int*)(ws + OFF_BBS_B);
    unsigned*       buckets = (unsigned*)(ws + OFF_BKT_B);
    unsigned short* btn     = (unsigned short*)(ws + OFF_BTN_B);
    unsigned short* bts     = (unsigned short*)(ws + OFF_BTS_B);
    unsigned short* T       = (unsigned short*)(ws + OFF_T_B);
    unsigned short* U       = (unsigned short*)(ws + OFF_U_B);

    hipMemsetAsync(cnt, 0, (size_t)NNODES * sizeof(int), stream);
    wconv<<<(DIM * DIM + 255) / 256, 256, 0, stream>>>(wn, wsf, btn, bts);

    int eb = (NEDGES + 255) / 256;
    hist<<<eb, 256, 0, stream>>>(edges, cnt);
    scan_partial<<<NSB, SCB, 0, stream>>>(cnt, bsum);
    scan_bsum<<<1, 256, 0, stream>>>(bsum, bbase, off);
    scan_final<<<NSB, SCB, 0, stream>>>(cnt, bbase, off, cursor);
    fill<<<eb, 256, 0, stream>>>(edges, cursor, buckets);

    transform<<<NODE_BLKS + REL_BLKS, 256, 0, stream>>>(nodes, rels, btn, bts, T, U, out);

    int gb = (NNODES * 64 + 255) / 256;
    gather<<<gb, 256, 0, stream>>>(T, U, off, buckets, nodes, wse, out);
}

// Round 6
// 136.317 us; speedup vs baseline: 1.3116x; 1.1592x over previous
//
#include <hip/hip_runtime.h>

// URGCN layer, MI355X — round 6.
// r5 post-mortem: transform was latency-bound on per-iteration GLOBAL B-frag
// loads (MfmaUtil 2.4%, VALUBusy 3.5%, HBM 16% — nothing busy). Fix: stage B
// in LDS once per block (padded rows, bank-conflict-free ds_read_b128), split
// T-GEMM and S-GEMM into two kernels, fold "+h" into the self weight:
// Sp = h @ (I + Wself).
//
// Algebra: msg_agg = (Σ_e T[src] + u[rel]) / deg, T = h@Wn (bf16 MFMA),
//          u = rel@Wn.  out = Sp + msg_agg, Sp = h@(I+Wself) (f32, in d_out).

constexpr int NNODES = 50000;
constexpr int NEDGES = 600000;
constexpr int NRELS  = 500;
constexpr int DIM    = 128;

constexpr int SCB = 256;
constexpr int NSB = (NNODES + SCB - 1) / SCB;   // 196

constexpr int NODE_BLKS = (NNODES + 63) / 64;   // 782
constexpr int REL_BLKS  = (NRELS  + 63) / 64;   // 8

constexpr int BP   = 136;  // LDS B row pitch in shorts (272B = 17 dwords, odd -> all banks)
constexpr int TPAD = 8;    // ldsT pitch pad (shorts)
constexpr int SPAD = 4;    // ldsS pitch pad (floats)

// ---------------- workspace layout (bytes) ----------------
constexpr size_t OFF_CNT_B = 0;                            // int[50000]
constexpr size_t OFF_OFF_B = 204800;                       // int[50001]
constexpr size_t OFF_CUR_B = 409600;                       // int[50000]
constexpr size_t OFF_BSM_B = 614400;                       // int[NSB]
constexpr size_t OFF_BBS_B = 618496;                       // int[256]
constexpr size_t OFF_BKT_B = 622592;                       // uint[600000]
constexpr size_t OFF_BTN_B = OFF_BKT_B + 2400000;          // ushort[128*128] Wn^T bf16
constexpr size_t OFF_BTS_B = OFF_BTN_B + 32768;            // ushort[128*128] (I+Ws)^T bf16
constexpr size_t OFF_T_B   = OFF_BTS_B + 32768;            // ushort[50000*128]
constexpr size_t OFF_U_B   = OFF_T_B + (size_t)NNODES * DIM * 2; // ushort[500*128]

typedef short s8f __attribute__((ext_vector_type(8)));   // 8 bf16 (4 VGPR)
typedef float f4  __attribute__((ext_vector_type(4)));   // MFMA acc

static __device__ __forceinline__ unsigned short f2bf(float f) {
    unsigned u = __builtin_bit_cast(unsigned, f);
    u += 0x7FFFu + ((u >> 16) & 1u);        // round-to-nearest-even
    return (unsigned short)(u >> 16);
}
static __device__ __forceinline__ float bflo(unsigned v) {
    return __builtin_bit_cast(float, v << 16);
}
static __device__ __forceinline__ float bfhi(unsigned v) {
    return __builtin_bit_cast(float, v & 0xFFFF0000u);
}

// ---------------------------------------------------------------------------
__global__ __launch_bounds__(256) void wconv(const float* __restrict__ wn,
                                             const float* __restrict__ wsf,
                                             unsigned short* __restrict__ btn,
                                             unsigned short* __restrict__ bts)
{
    int idx = blockIdx.x * 256 + threadIdx.x;
    if (idx >= DIM * DIM) return;
    int k = idx >> 7, j = idx & 127;
    btn[(size_t)j * DIM + k] = f2bf(wn[idx]);                        // Wn^T [col][k]
    bts[(size_t)j * DIM + k] = f2bf(wsf[idx] + (k == j ? 1.f : 0.f)); // (I+Ws)^T
}

__global__ __launch_bounds__(256) void hist(const int* __restrict__ edges,
                                            int* __restrict__ cnt)
{
    int e = blockIdx.x * 256 + threadIdx.x;
    if (e >= NEDGES) return;
    atomicAdd(cnt + edges[e * 3 + 2], 1);
}

__global__ __launch_bounds__(SCB) void scan_partial(const int* __restrict__ cnt,
                                                    int* __restrict__ bsum)
{
    int gid = blockIdx.x * SCB + threadIdx.x;
    int v = (gid < NNODES) ? cnt[gid] : 0;
    #pragma unroll
    for (int d = 32; d > 0; d >>= 1) v += __shfl_down(v, d, 64);
    __shared__ int ws[SCB / 64];
    if ((threadIdx.x & 63) == 0) ws[threadIdx.x >> 6] = v;
    __syncthreads();
    if (threadIdx.x == 0) {
        int s = 0;
        #pragma unroll
        for (int w = 0; w < SCB / 64; ++w) s += ws[w];
        bsum[blockIdx.x] = s;
    }
}

__global__ __launch_bounds__(256) void scan_bsum(const int* __restrict__ bsum,
                                                 int* __restrict__ bbase,
                                                 int* __restrict__ off)
{
    __shared__ int sh[256];
    int t = threadIdx.x;
    sh[t] = (t < NSB) ? bsum[t] : 0;
    __syncthreads();
    #pragma unroll
    for (int d = 1; d < 256; d <<= 1) {
        int u = (t >= d) ? sh[t - d] : 0;
        __syncthreads();
        sh[t] += u;
        __syncthreads();
    }
    bbase[t] = (t == 0) ? 0 : sh[t - 1];
    if (t == 255) off[NNODES] = sh[255];
}

__global__ __launch_bounds__(SCB) void scan_final(const int* __restrict__ cnt,
                                                  const int* __restrict__ bbase,
                                                  int* __restrict__ off,
                                                  int* __restrict__ cursor)
{
    __shared__ int sh[SCB];
    int t = threadIdx.x;
    int gid = blockIdx.x * SCB + t;
    sh[t] = (gid < NNODES) ? cnt[gid] : 0;
    __syncthreads();
    #pragma unroll
    for (int d = 1; d < SCB; d <<= 1) {
        int u = (t >= d) ? sh[t - d] : 0;
        __syncthreads();
        sh[t] += u;
        __syncthreads();
    }
    if (gid < NNODES) {
        int excl = bbase[blockIdx.x] + ((t == 0) ? 0 : sh[t - 1]);
        off[gid] = excl;
        cursor[gid] = excl;
    }
}

__global__ __launch_bounds__(256) void fill(const int* __restrict__ edges,
                                            int* __restrict__ cursor,
                                            unsigned* __restrict__ buckets)
{
    int e = blockIdx.x * 256 + threadIdx.x;
    if (e >= NEDGES) return;
    int src = edges[e * 3 + 0];
    int rel = edges[e * 3 + 1];
    int dst = edges[e * 3 + 2];
    int pos = atomicAdd(cursor + dst, 1);
    buckets[pos] = (unsigned)src | ((unsigned)rel << 16);
}

// ---------------------------------------------------------------------------
// Shared helpers for the two GEMM kernels.
// Stage a [col][k] bf16 128x128 weight into padded LDS (row pitch BP shorts).
static __device__ __forceinline__ void stage_B(const unsigned short* __restrict__ src,
                                               unsigned short* __restrict__ ldsB,
                                               int t)
{
    #pragma unroll
    for (int i = 0; i < 8; ++i) {
        int idx = t + i * 256;          // 2048 x 16B slots
        int col = idx >> 4;
        int slot = idx & 15;
        *(uint4*)(ldsB + (size_t)col * BP + slot * 8) =
            *(const uint4*)(src + (size_t)col * DIM + slot * 8);
    }
}

// Load + convert a 16-row A fragment set (4 x s8f covering k=0..127).
static __device__ __forceinline__ void load_A(const float* __restrict__ A,
                                              int arowc, int kg, s8f afrag[4])
{
    #pragma unroll
    for (int ks = 0; ks < 4; ++ks) {
        const float* p = A + (size_t)arowc * DIM + ks * 32 + kg * 8;
        float4 x = *(const float4*)p;
        float4 y = *(const float4*)(p + 4);
        s8f a;
        a[0] = (short)f2bf(x.x); a[1] = (short)f2bf(x.y);
        a[2] = (short)f2bf(x.z); a[3] = (short)f2bf(x.w);
        a[4] = (short)f2bf(y.x); a[5] = (short)f2bf(y.y);
        a[6] = (short)f2bf(y.z); a[7] = (short)f2bf(y.w);
        afrag[ks] = a;
    }
}

// ---------------------------------------------------------------------------
// t_kernel: T = nodes@Wn (bf16) for node blocks; U = rels@Wn for rel blocks.
// B staged once in LDS; MFMA fed by ds_read_b128; LDS-transposed bf16 stores.
// LDS: 34.8KB (B) + 17.4KB (T tile) = 52.2KB -> 3 blocks/CU.
// ---------------------------------------------------------------------------
__global__ __launch_bounds__(256) void t_kernel(
    const float* __restrict__ nodes, const float* __restrict__ rels,
    const unsigned short* __restrict__ btn,
    unsigned short* __restrict__ T, unsigned short* __restrict__ U)
{
    __shared__ __align__(16) unsigned short ldsB[DIM * BP];
    __shared__ __align__(16) unsigned short ldsT[4][16][DIM + TPAD];

    int blk = blockIdx.x;
    bool isRel = blk >= NODE_BLKS;
    const float* A = isRel ? rels : nodes;
    int nrows = isRel ? NRELS : NNODES;
    int rowbase = (isRel ? (blk - NODE_BLKS) : blk) * 64;

    int t  = threadIdx.x;
    int wv = t >> 6;
    int l  = t & 63;
    int r0 = rowbase + wv * 16;
    int m  = l & 15;
    int kg = l >> 4;
    int arow  = r0 + m;
    int arowc = arow < nrows ? arow : nrows - 1;

    s8f afrag[4];
    load_A(A, arowc, kg, afrag);
    stage_B(btn, ldsB, t);
    __syncthreads();

    #pragma unroll 2
    for (int ct = 0; ct < 8; ++ct) {
        int col = ct * 16 + m;
        const unsigned short* bp = ldsB + (size_t)col * BP + kg * 8;
        f4 acc = {0.f, 0.f, 0.f, 0.f};
        #pragma unroll
        for (int ks = 0; ks < 4; ++ks)
            acc = __builtin_amdgcn_mfma_f32_16x16x32_bf16(afrag[ks], *(const s8f*)(bp + ks * 32), acc, 0, 0, 0);
        #pragma unroll
        for (int r = 0; r < 4; ++r)
            ldsT[wv][kg * 4 + r][col] = f2bf(acc[r]);
    }
    __syncthreads();

    unsigned short* Tout = isRel ? U : T;
    #pragma unroll
    for (int p = 0; p < 4; ++p) {
        int row = p * 4 + kg;
        int rg  = r0 + row;
        if (rg < nrows)
            *(uint4*)(Tout + (size_t)rg * DIM + m * 8) =
                *(const uint4*)&ldsT[wv][row][m * 8];
    }
}

// ---------------------------------------------------------------------------
// s_kernel: Sp = nodes @ (I + Wself)  (f32, straight into d_out).
// LDS: 34.8KB (B) + 33.8KB (S tile) = 68.6KB -> 2 blocks/CU.
// ---------------------------------------------------------------------------
__global__ __launch_bounds__(256) void s_kernel(
    const float* __restrict__ nodes,
    const unsigned short* __restrict__ bts,
    float* __restrict__ Sp)
{
    __shared__ __align__(16) unsigned short ldsB[DIM * BP];
    __shared__ __align__(16) float          ldsS[4][16][DIM + SPAD];

    int rowbase = blockIdx.x * 64;
    int t  = threadIdx.x;
    int wv = t >> 6;
    int l  = t & 63;
    int r0 = rowbase + wv * 16;
    int m  = l & 15;
    int kg = l >> 4;
    int arow  = r0 + m;
    int arowc = arow < NNODES ? arow : NNODES - 1;

    s8f afrag[4];
    load_A(nodes, arowc, kg, afrag);
    stage_B(bts, ldsB, t);
    __syncthreads();

    #pragma unroll 2
    for (int ct = 0; ct < 8; ++ct) {
        int col = ct * 16 + m;
        const unsigned short* bp = ldsB + (size_t)col * BP + kg * 8;
        f4 acc = {0.f, 0.f, 0.f, 0.f};
        #pragma unroll
        for (int ks = 0; ks < 4; ++ks)
            acc = __builtin_amdgcn_mfma_f32_16x16x32_bf16(afrag[ks], *(const s8f*)(bp + ks * 32), acc, 0, 0, 0);
        #pragma unroll
        for (int r = 0; r < 4; ++r)
            ldsS[wv][kg * 4 + r][col] = acc[r];
    }
    __syncthreads();

    #pragma unroll
    for (int p = 0; p < 4; ++p) {
        int row = p * 4 + kg;
        int rg  = r0 + row;
        if (rg < NNODES) {
            float* orow = Sp + (size_t)rg * DIM;
            #pragma unroll
            for (int j = 0; j < 2; ++j) {
                int c0 = m * 4 + j * 64;
                *(float4*)(orow + c0) = *(const float4*)&ldsS[wv][row][c0];
            }
        }
    }
}

// ---------------------------------------------------------------------------
// gather: full wave per node; halves walk alternate bucket entries; lane
// (l&31) covers 4 bf16 columns (8B). out = Sp[n] + acc/deg (in-place d_out).
// ---------------------------------------------------------------------------
__global__ __launch_bounds__(256) void gather(
    const unsigned short* __restrict__ T, const unsigned short* __restrict__ U,
    const int* __restrict__ off, const unsigned* __restrict__ buckets,
    const float* __restrict__ nodes, const float* __restrict__ wse,
    float* __restrict__ outp)
{
    int tid = blockIdx.x * 256 + threadIdx.x;
    int n = tid >> 6;
    if (n >= NNODES) return;
    int l = threadIdx.x & 63;
    int half = l >> 5;
    int c = l & 31;

    int beg = off[n];
    int end = off[n + 1];

    if (beg == end) {
        // rare (~e^-12 per node): out = h + h @ Wse, straight f32 matvec
        if (half == 0) {
            float s0 = 0, s1 = 0, s2 = 0, s3 = 0;
            for (int k = 0; k < DIM; ++k) {
                float hk = nodes[(size_t)n * DIM + k];
                const float* wr = wse + (size_t)k * DIM + c * 4;
                s0 += hk * wr[0]; s1 += hk * wr[1];
                s2 += hk * wr[2]; s3 += hk * wr[3];
            }
            float4 hv = *(const float4*)(nodes + (size_t)n * DIM + c * 4);
            float4 o = { hv.x + s0, hv.y + s1, hv.z + s2, hv.w + s3 };
            *(float4*)(outp + (size_t)n * DIM + c * 4) = o;
        }
        return;
    }

    float4 acc = make_float4(0.f, 0.f, 0.f, 0.f);
    int i = beg + half;
    for (; i + 2 < end; i += 4) {
        unsigned b0 = buckets[i];
        unsigned b1 = buckets[i + 2];
        uint2 t0 = *(const uint2*)(T + (size_t)(b0 & 0xFFFFu) * DIM + c * 4);
        uint2 u0 = *(const uint2*)(U + (size_t)(b0 >> 16)     * DIM + c * 4);
        uint2 t1 = *(const uint2*)(T + (size_t)(b1 & 0xFFFFu) * DIM + c * 4);
        uint2 u1 = *(const uint2*)(U + (size_t)(b1 >> 16)     * DIM + c * 4);
        acc.x += bflo(t0.x) + bflo(u0.x); acc.y += bfhi(t0.x) + bfhi(u0.x);
        acc.z += bflo(t0.y) + bflo(u0.y); acc.w += bfhi(t0.y) + bfhi(u0.y);
        acc.x += bflo(t1.x) + bflo(u1.x); acc.y += bfhi(t1.x) + bfhi(u1.x);
        acc.z += bflo(t1.y) + bflo(u1.y); acc.w += bfhi(t1.y) + bfhi(u1.y);
    }
    if (i < end) {
        unsigned b0 = buckets[i];
        uint2 t0 = *(const uint2*)(T + (size_t)(b0 & 0xFFFFu) * DIM + c * 4);
        uint2 u0 = *(const uint2*)(U + (size_t)(b0 >> 16)     * DIM + c * 4);
        acc.x += bflo(t0.x) + bflo(u0.x); acc.y += bfhi(t0.x) + bfhi(u0.x);
        acc.z += bflo(t0.y) + bflo(u0.y); acc.w += bfhi(t0.y) + bfhi(u0.y);
    }

    acc.x += __shfl_xor(acc.x, 32, 64);
    acc.y += __shfl_xor(acc.y, 32, 64);
    acc.z += __shfl_xor(acc.z, 32, 64);
    acc.w += __shfl_xor(acc.w, 32, 64);

    if (half == 0) {
        float inv = 1.0f / (float)(end - beg);
        float4 sp = *(const float4*)(outp + (size_t)n * DIM + c * 4);
        float4 o = { sp.x + acc.x * inv, sp.y + acc.y * inv,
                     sp.z + acc.z * inv, sp.w + acc.w * inv };
        *(float4*)(outp + (size_t)n * DIM + c * 4) = o;
    }
}

// ---------------------------------------------------------------------------
extern "C" void kernel_launch(void* const* d_in, const int* in_sizes, int n_in,
                              void* d_out, int out_size, void* d_ws, size_t ws_size,
                              hipStream_t stream)
{
    const float* nodes = (const float*)d_in[0];
    const float* rels  = (const float*)d_in[1];
    const int*   edges = (const int*)d_in[2];
    const float* wn    = (const float*)d_in[3];
    const float* wsf   = (const float*)d_in[4];
    const float* wse   = (const float*)d_in[5];
    float* out = (float*)d_out;

    char* ws = (char*)d_ws;
    int*            cnt     = (int*)(ws + OFF_CNT_B);
    int*            off     = (int*)(ws + OFF_OFF_B);
    int*            cursor  = (int*)(ws + OFF_CUR_B);
    int*            bsum    = (int*)(ws + OFF_BSM_B);
    int*            bbase   = (int*)(ws + OFF_BBS_B);
    unsigned*       buckets = (unsigned*)(ws + OFF_BKT_B);
    unsigned short* btn     = (unsigned short*)(ws + OFF_BTN_B);
    unsigned short* bts     = (unsigned short*)(ws + OFF_BTS_B);
    unsigned short* T       = (unsigned short*)(ws + OFF_T_B);
    unsigned short* U       = (unsigned short*)(ws + OFF_U_B);

    hipMemsetAsync(cnt, 0, (size_t)NNODES * sizeof(int), stream);
    wconv<<<(DIM * DIM + 255) / 256, 256, 0, stream>>>(wn, wsf, btn, bts);

    int eb = (NEDGES + 255) / 256;
    hist<<<eb, 256, 0, stream>>>(edges, cnt);
    scan_partial<<<NSB, SCB, 0, stream>>>(cnt, bsum);
    scan_bsum<<<1, 256, 0, stream>>>(bsum, bbase, off);
    scan_final<<<NSB, SCB, 0, stream>>>(cnt, bbase, off, cursor);
    fill<<<eb, 256, 0, stream>>>(edges, cursor, buckets);

    t_kernel<<<NODE_BLKS + REL_BLKS, 256, 0, stream>>>(nodes, rels, btn, T, U);
    s_kernel<<<NODE_BLKS, 256, 0, stream>>>(nodes, bts, out);

    int gb = (NNODES * 64 + 255) / 256;
    gather<<<gb, 256, 0, stream>>>(T, U, off, buckets, nodes, wse, out);
}

// Round 7
// 133.547 us; speedup vs baseline: 1.3388x; 1.0207x over previous
//
#include <hip/hip_runtime.h>

// URGCN layer, MI355X — round 7.
// r6 post-mortem: hipMemsetAsync(cnt, 200KB) dispatched rocclr's
// fillBufferAligned at ~41us/replay (30% of total!). Replace with a fused
// prep kernel (weight convert + cnt zero) — one dispatch, ~3us.
//
// Algebra: msg_agg = (Σ_e T[src] + u[rel]) / deg, T = h@Wn (bf16 MFMA),
//          u = rel@Wn.  out = Sp + msg_agg, Sp = h@(I+Wself) (f32, in d_out).

constexpr int NNODES = 50000;
constexpr int NEDGES = 600000;
constexpr int NRELS  = 500;
constexpr int DIM    = 128;

constexpr int SCB = 256;
constexpr int NSB = (NNODES + SCB - 1) / SCB;   // 196

constexpr int NODE_BLKS = (NNODES + 63) / 64;   // 782
constexpr int REL_BLKS  = (NRELS  + 63) / 64;   // 8

constexpr int BP   = 136;  // LDS B row pitch in shorts (272B -> all banks)
constexpr int TPAD = 8;    // ldsT pitch pad (shorts)
constexpr int SPAD = 4;    // ldsS pitch pad (floats)

// prep kernel geometry
constexpr int WCONV_BLKS = (DIM * DIM + 255) / 256;            // 64
constexpr int ZERO_INT4S = (NNODES + 3) / 4;                   // 12500 int4
constexpr int ZERO_BLKS  = (ZERO_INT4S + 255) / 256;           // 49
constexpr int PREP_BLKS  = WCONV_BLKS + ZERO_BLKS;             // 113

// ---------------- workspace layout (bytes) ----------------
constexpr size_t OFF_CNT_B = 0;                            // int[50000] (pad to 50004)
constexpr size_t OFF_OFF_B = 204800;                       // int[50001]
constexpr size_t OFF_CUR_B = 409600;                       // int[50000]
constexpr size_t OFF_BSM_B = 614400;                       // int[NSB]
constexpr size_t OFF_BBS_B = 618496;                       // int[256]
constexpr size_t OFF_BKT_B = 622592;                       // uint[600000]
constexpr size_t OFF_BTN_B = OFF_BKT_B + 2400000;          // ushort[128*128] Wn^T bf16
constexpr size_t OFF_BTS_B = OFF_BTN_B + 32768;            // ushort[128*128] (I+Ws)^T bf16
constexpr size_t OFF_T_B   = OFF_BTS_B + 32768;            // ushort[50000*128]
constexpr size_t OFF_U_B   = OFF_T_B + (size_t)NNODES * DIM * 2; // ushort[500*128]

typedef short s8f __attribute__((ext_vector_type(8)));   // 8 bf16 (4 VGPR)
typedef float f4  __attribute__((ext_vector_type(4)));   // MFMA acc

static __device__ __forceinline__ unsigned short f2bf(float f) {
    unsigned u = __builtin_bit_cast(unsigned, f);
    u += 0x7FFFu + ((u >> 16) & 1u);        // round-to-nearest-even
    return (unsigned short)(u >> 16);
}
static __device__ __forceinline__ float bflo(unsigned v) {
    return __builtin_bit_cast(float, v << 16);
}
static __device__ __forceinline__ float bfhi(unsigned v) {
    return __builtin_bit_cast(float, v & 0xFFFF0000u);
}

// ---------------------------------------------------------------------------
// prep: blocks [0,64) convert weights; blocks [64,113) zero cnt (int4).
__global__ __launch_bounds__(256) void prep(const float* __restrict__ wn,
                                            const float* __restrict__ wsf,
                                            unsigned short* __restrict__ btn,
                                            unsigned short* __restrict__ bts,
                                            int4* __restrict__ cnt4)
{
    int b = blockIdx.x;
    if (b < WCONV_BLKS) {
        int idx = b * 256 + threadIdx.x;
        int k = idx >> 7, j = idx & 127;
        btn[(size_t)j * DIM + k] = f2bf(wn[idx]);                         // Wn^T
        bts[(size_t)j * DIM + k] = f2bf(wsf[idx] + (k == j ? 1.f : 0.f)); // (I+Ws)^T
    } else {
        int idx = (b - WCONV_BLKS) * 256 + threadIdx.x;
        if (idx < ZERO_INT4S) cnt4[idx] = make_int4(0, 0, 0, 0);
    }
}

__global__ __launch_bounds__(256) void hist(const int* __restrict__ edges,
                                            int* __restrict__ cnt)
{
    int e = blockIdx.x * 256 + threadIdx.x;
    if (e >= NEDGES) return;
    atomicAdd(cnt + edges[e * 3 + 2], 1);
}

__global__ __launch_bounds__(SCB) void scan_partial(const int* __restrict__ cnt,
                                                    int* __restrict__ bsum)
{
    int gid = blockIdx.x * SCB + threadIdx.x;
    int v = (gid < NNODES) ? cnt[gid] : 0;
    #pragma unroll
    for (int d = 32; d > 0; d >>= 1) v += __shfl_down(v, d, 64);
    __shared__ int ws[SCB / 64];
    if ((threadIdx.x & 63) == 0) ws[threadIdx.x >> 6] = v;
    __syncthreads();
    if (threadIdx.x == 0) {
        int s = 0;
        #pragma unroll
        for (int w = 0; w < SCB / 64; ++w) s += ws[w];
        bsum[blockIdx.x] = s;
    }
}

__global__ __launch_bounds__(256) void scan_bsum(const int* __restrict__ bsum,
                                                 int* __restrict__ bbase,
                                                 int* __restrict__ off)
{
    __shared__ int sh[256];
    int t = threadIdx.x;
    sh[t] = (t < NSB) ? bsum[t] : 0;
    __syncthreads();
    #pragma unroll
    for (int d = 1; d < 256; d <<= 1) {
        int u = (t >= d) ? sh[t - d] : 0;
        __syncthreads();
        sh[t] += u;
        __syncthreads();
    }
    bbase[t] = (t == 0) ? 0 : sh[t - 1];
    if (t == 255) off[NNODES] = sh[255];
}

__global__ __launch_bounds__(SCB) void scan_final(const int* __restrict__ cnt,
                                                  const int* __restrict__ bbase,
                                                  int* __restrict__ off,
                                                  int* __restrict__ cursor)
{
    __shared__ int sh[SCB];
    int t = threadIdx.x;
    int gid = blockIdx.x * SCB + t;
    sh[t] = (gid < NNODES) ? cnt[gid] : 0;
    __syncthreads();
    #pragma unroll
    for (int d = 1; d < SCB; d <<= 1) {
        int u = (t >= d) ? sh[t - d] : 0;
        __syncthreads();
        sh[t] += u;
        __syncthreads();
    }
    if (gid < NNODES) {
        int excl = bbase[blockIdx.x] + ((t == 0) ? 0 : sh[t - 1]);
        off[gid] = excl;
        cursor[gid] = excl;
    }
}

__global__ __launch_bounds__(256) void fill(const int* __restrict__ edges,
                                            int* __restrict__ cursor,
                                            unsigned* __restrict__ buckets)
{
    int e = blockIdx.x * 256 + threadIdx.x;
    if (e >= NEDGES) return;
    int src = edges[e * 3 + 0];
    int rel = edges[e * 3 + 1];
    int dst = edges[e * 3 + 2];
    int pos = atomicAdd(cursor + dst, 1);
    buckets[pos] = (unsigned)src | ((unsigned)rel << 16);
}

// ---------------------------------------------------------------------------
// Stage a [col][k] bf16 128x128 weight into padded LDS (row pitch BP shorts).
static __device__ __forceinline__ void stage_B(const unsigned short* __restrict__ src,
                                               unsigned short* __restrict__ ldsB,
                                               int t)
{
    #pragma unroll
    for (int i = 0; i < 8; ++i) {
        int idx = t + i * 256;          // 2048 x 16B slots
        int col = idx >> 4;
        int slot = idx & 15;
        *(uint4*)(ldsB + (size_t)col * BP + slot * 8) =
            *(const uint4*)(src + (size_t)col * DIM + slot * 8);
    }
}

// Load + convert a 16-row A fragment set (4 x s8f covering k=0..127).
static __device__ __forceinline__ void load_A(const float* __restrict__ A,
                                              int arowc, int kg, s8f afrag[4])
{
    #pragma unroll
    for (int ks = 0; ks < 4; ++ks) {
        const float* p = A + (size_t)arowc * DIM + ks * 32 + kg * 8;
        float4 x = *(const float4*)p;
        float4 y = *(const float4*)(p + 4);
        s8f a;
        a[0] = (short)f2bf(x.x); a[1] = (short)f2bf(x.y);
        a[2] = (short)f2bf(x.z); a[3] = (short)f2bf(x.w);
        a[4] = (short)f2bf(y.x); a[5] = (short)f2bf(y.y);
        a[6] = (short)f2bf(y.z); a[7] = (short)f2bf(y.w);
        afrag[ks] = a;
    }
}

// ---------------------------------------------------------------------------
// t_kernel: T = nodes@Wn (bf16) for node blocks; U = rels@Wn for rel blocks.
// B staged once in LDS; MFMA fed by ds_read_b128; LDS-transposed bf16 stores.
// ---------------------------------------------------------------------------
__global__ __launch_bounds__(256) void t_kernel(
    const float* __restrict__ nodes, const float* __restrict__ rels,
    const unsigned short* __restrict__ btn,
    unsigned short* __restrict__ T, unsigned short* __restrict__ U)
{
    __shared__ __align__(16) unsigned short ldsB[DIM * BP];
    __shared__ __align__(16) unsigned short ldsT[4][16][DIM + TPAD];

    int blk = blockIdx.x;
    bool isRel = blk >= NODE_BLKS;
    const float* A = isRel ? rels : nodes;
    int nrows = isRel ? NRELS : NNODES;
    int rowbase = (isRel ? (blk - NODE_BLKS) : blk) * 64;

    int t  = threadIdx.x;
    int wv = t >> 6;
    int l  = t & 63;
    int r0 = rowbase + wv * 16;
    int m  = l & 15;
    int kg = l >> 4;
    int arow  = r0 + m;
    int arowc = arow < nrows ? arow : nrows - 1;

    s8f afrag[4];
    load_A(A, arowc, kg, afrag);
    stage_B(btn, ldsB, t);
    __syncthreads();

    #pragma unroll 2
    for (int ct = 0; ct < 8; ++ct) {
        int col = ct * 16 + m;
        const unsigned short* bp = ldsB + (size_t)col * BP + kg * 8;
        f4 acc = {0.f, 0.f, 0.f, 0.f};
        #pragma unroll
        for (int ks = 0; ks < 4; ++ks)
            acc = __builtin_amdgcn_mfma_f32_16x16x32_bf16(afrag[ks], *(const s8f*)(bp + ks * 32), acc, 0, 0, 0);
        #pragma unroll
        for (int r = 0; r < 4; ++r)
            ldsT[wv][kg * 4 + r][col] = f2bf(acc[r]);
    }
    __syncthreads();

    unsigned short* Tout = isRel ? U : T;
    #pragma unroll
    for (int p = 0; p < 4; ++p) {
        int row = p * 4 + kg;
        int rg  = r0 + row;
        if (rg < nrows)
            *(uint4*)(Tout + (size_t)rg * DIM + m * 8) =
                *(const uint4*)&ldsT[wv][row][m * 8];
    }
}

// ---------------------------------------------------------------------------
// s_kernel: Sp = nodes @ (I + Wself)  (f32, straight into d_out).
// ---------------------------------------------------------------------------
__global__ __launch_bounds__(256) void s_kernel(
    const float* __restrict__ nodes,
    const unsigned short* __restrict__ bts,
    float* __restrict__ Sp)
{
    __shared__ __align__(16) unsigned short ldsB[DIM * BP];
    __shared__ __align__(16) float          ldsS[4][16][DIM + SPAD];

    int rowbase = blockIdx.x * 64;
    int t  = threadIdx.x;
    int wv = t >> 6;
    int l  = t & 63;
    int r0 = rowbase + wv * 16;
    int m  = l & 15;
    int kg = l >> 4;
    int arow  = r0 + m;
    int arowc = arow < NNODES ? arow : NNODES - 1;

    s8f afrag[4];
    load_A(nodes, arowc, kg, afrag);
    stage_B(bts, ldsB, t);
    __syncthreads();

    #pragma unroll 2
    for (int ct = 0; ct < 8; ++ct) {
        int col = ct * 16 + m;
        const unsigned short* bp = ldsB + (size_t)col * BP + kg * 8;
        f4 acc = {0.f, 0.f, 0.f, 0.f};
        #pragma unroll
        for (int ks = 0; ks < 4; ++ks)
            acc = __builtin_amdgcn_mfma_f32_16x16x32_bf16(afrag[ks], *(const s8f*)(bp + ks * 32), acc, 0, 0, 0);
        #pragma unroll
        for (int r = 0; r < 4; ++r)
            ldsS[wv][kg * 4 + r][col] = acc[r];
    }
    __syncthreads();

    #pragma unroll
    for (int p = 0; p < 4; ++p) {
        int row = p * 4 + kg;
        int rg  = r0 + row;
        if (rg < NNODES) {
            float* orow = Sp + (size_t)rg * DIM;
            #pragma unroll
            for (int j = 0; j < 2; ++j) {
                int c0 = m * 4 + j * 64;
                *(float4*)(orow + c0) = *(const float4*)&ldsS[wv][row][c0];
            }
        }
    }
}

// ---------------------------------------------------------------------------
// gather: full wave per node; halves walk alternate bucket entries; lane
// (l&31) covers 4 bf16 columns (8B). out = Sp[n] + acc/deg (in-place d_out).
// ---------------------------------------------------------------------------
__global__ __launch_bounds__(256) void gather(
    const unsigned short* __restrict__ T, const unsigned short* __restrict__ U,
    const int* __restrict__ off, const unsigned* __restrict__ buckets,
    const float* __restrict__ nodes, const float* __restrict__ wse,
    float* __restrict__ outp)
{
    int tid = blockIdx.x * 256 + threadIdx.x;
    int n = tid >> 6;
    if (n >= NNODES) return;
    int l = threadIdx.x & 63;
    int half = l >> 5;
    int c = l & 31;

    int beg = off[n];
    int end = off[n + 1];

    if (beg == end) {
        // rare (~e^-12 per node): out = h + h @ Wse, straight f32 matvec
        if (half == 0) {
            float s0 = 0, s1 = 0, s2 = 0, s3 = 0;
            for (int k = 0; k < DIM; ++k) {
                float hk = nodes[(size_t)n * DIM + k];
                const float* wr = wse + (size_t)k * DIM + c * 4;
                s0 += hk * wr[0]; s1 += hk * wr[1];
                s2 += hk * wr[2]; s3 += hk * wr[3];
            }
            float4 hv = *(const float4*)(nodes + (size_t)n * DIM + c * 4);
            float4 o = { hv.x + s0, hv.y + s1, hv.z + s2, hv.w + s3 };
            *(float4*)(outp + (size_t)n * DIM + c * 4) = o;
        }
        return;
    }

    float4 acc = make_float4(0.f, 0.f, 0.f, 0.f);
    int i = beg + half;
    for (; i + 2 < end; i += 4) {
        unsigned b0 = buckets[i];
        unsigned b1 = buckets[i + 2];
        uint2 t0 = *(const uint2*)(T + (size_t)(b0 & 0xFFFFu) * DIM + c * 4);
        uint2 u0 = *(const uint2*)(U + (size_t)(b0 >> 16)     * DIM + c * 4);
        uint2 t1 = *(const uint2*)(T + (size_t)(b1 & 0xFFFFu) * DIM + c * 4);
        uint2 u1 = *(const uint2*)(U + (size_t)(b1 >> 16)     * DIM + c * 4);
        acc.x += bflo(t0.x) + bflo(u0.x); acc.y += bfhi(t0.x) + bfhi(u0.x);
        acc.z += bflo(t0.y) + bflo(u0.y); acc.w += bfhi(t0.y) + bfhi(u0.y);
        acc.x += bflo(t1.x) + bflo(u1.x); acc.y += bfhi(t1.x) + bfhi(u1.x);
        acc.z += bflo(t1.y) + bflo(u1.y); acc.w += bfhi(t1.y) + bfhi(u1.y);
    }
    if (i < end) {
        unsigned b0 = buckets[i];
        uint2 t0 = *(const uint2*)(T + (size_t)(b0 & 0xFFFFu) * DIM + c * 4);
        uint2 u0 = *(const uint2*)(U + (size_t)(b0 >> 16)     * DIM + c * 4);
        acc.x += bflo(t0.x) + bflo(u0.x); acc.y += bfhi(t0.x) + bfhi(u0.x);
        acc.z += bflo(t0.y) + bflo(u0.y); acc.w += bfhi(t0.y) + bfhi(u0.y);
    }

    acc.x += __shfl_xor(acc.x, 32, 64);
    acc.y += __shfl_xor(acc.y, 32, 64);
    acc.z += __shfl_xor(acc.z, 32, 64);
    acc.w += __shfl_xor(acc.w, 32, 64);

    if (half == 0) {
        float inv = 1.0f / (float)(end - beg);
        float4 sp = *(const float4*)(outp + (size_t)n * DIM + c * 4);
        float4 o = { sp.x + acc.x * inv, sp.y + acc.y * inv,
                     sp.z + acc.z * inv, sp.w + acc.w * inv };
        *(float4*)(outp + (size_t)n * DIM + c * 4) = o;
    }
}

// ---------------------------------------------------------------------------
extern "C" void kernel_launch(void* const* d_in, const int* in_sizes, int n_in,
                              void* d_out, int out_size, void* d_ws, size_t ws_size,
                              hipStream_t stream)
{
    const float* nodes = (const float*)d_in[0];
    const float* rels  = (const float*)d_in[1];
    const int*   edges = (const int*)d_in[2];
    const float* wn    = (const float*)d_in[3];
    const float* wsf   = (const float*)d_in[4];
    const float* wse   = (const float*)d_in[5];
    float* out = (float*)d_out;

    char* ws = (char*)d_ws;
    int*            cnt     = (int*)(ws + OFF_CNT_B);
    int*            off     = (int*)(ws + OFF_OFF_B);
    int*            cursor  = (int*)(ws + OFF_CUR_B);
    int*            bsum    = (int*)(ws + OFF_BSM_B);
    int*            bbase   = (int*)(ws + OFF_BBS_B);
    unsigned*       buckets = (unsigned*)(ws + OFF_BKT_B);
    unsigned short* btn     = (unsigned short*)(ws + OFF_BTN_B);
    unsigned short* bts     = (unsigned short*)(ws + OFF_BTS_B);
    unsigned short* T       = (unsigned short*)(ws + OFF_T_B);
    unsigned short* U       = (unsigned short*)(ws + OFF_U_B);

    prep<<<PREP_BLKS, 256, 0, stream>>>(wn, wsf, btn, bts, (int4*)cnt);

    int eb = (NEDGES + 255) / 256;
    hist<<<eb, 256, 0, stream>>>(edges, cnt);
    scan_partial<<<NSB, SCB, 0, stream>>>(cnt, bsum);
    scan_bsum<<<1, 256, 0, stream>>>(bsum, bbase, off);
    scan_final<<<NSB, SCB, 0, stream>>>(cnt, bbase, off, cursor);
    fill<<<eb, 256, 0, stream>>>(edges, cursor, buckets);

    t_kernel<<<NODE_BLKS + REL_BLKS, 256, 0, stream>>>(nodes, rels, btn, T, U);
    s_kernel<<<NODE_BLKS, 256, 0, stream>>>(nodes, bts, out);

    int gb = (NNODES * 64 + 255) / 256;
    gather<<<gb, 256, 0, stream>>>(T, U, off, buckets, nodes, wse, out);
}

// Round 8
// 129.330 us; speedup vs baseline: 1.3824x; 1.0326x over previous
//
#include <hip/hip_runtime.h>

// URGCN layer, MI355X — round 8.
// r7 post-mortem: the 41us fillBufferAligned entries are the HARNESS's 0xAA
// poison of d_ws (268MB @ 6.5TB/s), outside the timed path — r6's theory was
// wrong; our own memset was ~2us. This round: fuse t+s GEMMs (nodes read once,
// B restaged in-place), fold scan_bsum into scan_final, deepen gather pipeline.
//
// Algebra: msg_agg = (Σ_e T[src] + u[rel]) / deg, T = h@Wn (bf16 MFMA),
//          u = rel@Wn.  out = Sp + msg_agg, Sp = h@(I+Wself) (f32, in d_out).

constexpr int NNODES = 50000;
constexpr int NEDGES = 600000;
constexpr int NRELS  = 500;
constexpr int DIM    = 128;

constexpr int SCB = 256;
constexpr int NSB = (NNODES + SCB - 1) / SCB;   // 196

constexpr int NODE_BLKS = (NNODES + 63) / 64;   // 782
constexpr int REL_BLKS  = (NRELS  + 63) / 64;   // 8

constexpr int BP   = 136;  // LDS B row pitch in shorts (272B -> all banks)
constexpr int TPAD = 8;    // ldsT pitch pad (shorts)
constexpr int SPAD = 4;    // ldsS pitch pad (floats)

// prep kernel geometry
constexpr int WCONV_BLKS = (DIM * DIM + 255) / 256;            // 64
constexpr int ZERO_INT4S = (NNODES + 3) / 4;                   // 12500 int4
constexpr int ZERO_BLKS  = (ZERO_INT4S + 255) / 256;           // 49
constexpr int PREP_BLKS  = WCONV_BLKS + ZERO_BLKS;             // 113

// ---------------- workspace layout (bytes) ----------------
constexpr size_t OFF_CNT_B = 0;                            // int[50000] (pad to 50004)
constexpr size_t OFF_OFF_B = 204800;                       // int[50001]
constexpr size_t OFF_CUR_B = 409600;                       // int[50000]
constexpr size_t OFF_BSM_B = 614400;                       // int[NSB]
constexpr size_t OFF_BKT_B = 622592;                       // uint[600000]
constexpr size_t OFF_BTN_B = OFF_BKT_B + 2400000;          // ushort[128*128] Wn^T bf16
constexpr size_t OFF_BTS_B = OFF_BTN_B + 32768;            // ushort[128*128] (I+Ws)^T bf16
constexpr size_t OFF_T_B   = OFF_BTS_B + 32768;            // ushort[50000*128]
constexpr size_t OFF_U_B   = OFF_T_B + (size_t)NNODES * DIM * 2; // ushort[500*128]

typedef short s8f __attribute__((ext_vector_type(8)));   // 8 bf16 (4 VGPR)
typedef float f4  __attribute__((ext_vector_type(4)));   // MFMA acc

static __device__ __forceinline__ unsigned short f2bf(float f) {
    unsigned u = __builtin_bit_cast(unsigned, f);
    u += 0x7FFFu + ((u >> 16) & 1u);        // round-to-nearest-even
    return (unsigned short)(u >> 16);
}
static __device__ __forceinline__ float bflo(unsigned v) {
    return __builtin_bit_cast(float, v << 16);
}
static __device__ __forceinline__ float bfhi(unsigned v) {
    return __builtin_bit_cast(float, v & 0xFFFF0000u);
}

// ---------------------------------------------------------------------------
// prep: blocks [0,64) convert weights; blocks [64,113) zero cnt (int4).
__global__ __launch_bounds__(256) void prep(const float* __restrict__ wn,
                                            const float* __restrict__ wsf,
                                            unsigned short* __restrict__ btn,
                                            unsigned short* __restrict__ bts,
                                            int4* __restrict__ cnt4)
{
    int b = blockIdx.x;
    if (b < WCONV_BLKS) {
        int idx = b * 256 + threadIdx.x;
        int k = idx >> 7, j = idx & 127;
        btn[(size_t)j * DIM + k] = f2bf(wn[idx]);                         // Wn^T
        bts[(size_t)j * DIM + k] = f2bf(wsf[idx] + (k == j ? 1.f : 0.f)); // (I+Ws)^T
    } else {
        int idx = (b - WCONV_BLKS) * 256 + threadIdx.x;
        if (idx < ZERO_INT4S) cnt4[idx] = make_int4(0, 0, 0, 0);
    }
}

__global__ __launch_bounds__(256) void hist(const int* __restrict__ edges,
                                            int* __restrict__ cnt)
{
    int e = blockIdx.x * 256 + threadIdx.x;
    if (e >= NEDGES) return;
    atomicAdd(cnt + edges[e * 3 + 2], 1);
}

// --- scan phase 1: per-block sums of cnt ---
__global__ __launch_bounds__(SCB) void scan_partial(const int* __restrict__ cnt,
                                                    int* __restrict__ bsum)
{
    int gid = blockIdx.x * SCB + threadIdx.x;
    int v = (gid < NNODES) ? cnt[gid] : 0;
    #pragma unroll
    for (int d = 32; d > 0; d >>= 1) v += __shfl_down(v, d, 64);
    __shared__ int ws[SCB / 64];
    if ((threadIdx.x & 63) == 0) ws[threadIdx.x >> 6] = v;
    __syncthreads();
    if (threadIdx.x == 0) {
        int s = 0;
        #pragma unroll
        for (int w = 0; w < SCB / 64; ++w) s += ws[w];
        bsum[blockIdx.x] = s;
    }
}

// --- scan phase 2 (merged): block base by inline reduction of bsum[<b],
//     then block-local exclusive scan. off[NNODES] is the constant NEDGES. ---
__global__ __launch_bounds__(SCB) void scan_final(const int* __restrict__ cnt,
                                                  const int* __restrict__ bsum,
                                                  int* __restrict__ off,
                                                  int* __restrict__ cursor)
{
    __shared__ int sh[SCB];
    int t = threadIdx.x;
    int b = blockIdx.x;

    // base = sum of bsum[0..b-1]  (196 ints, L2-hit)
    sh[t] = (t < b && t < NSB) ? bsum[t] : 0;
    __syncthreads();
    #pragma unroll
    for (int d = 128; d > 0; d >>= 1) {
        if (t < d) sh[t] += sh[t + d];
        __syncthreads();
    }
    int base = sh[0];
    __syncthreads();

    int gid = b * SCB + t;
    sh[t] = (gid < NNODES) ? cnt[gid] : 0;
    __syncthreads();
    #pragma unroll
    for (int d = 1; d < SCB; d <<= 1) {
        int u = (t >= d) ? sh[t - d] : 0;
        __syncthreads();
        sh[t] += u;
        __syncthreads();
    }
    if (gid < NNODES) {
        int excl = base + ((t == 0) ? 0 : sh[t - 1]);
        off[gid] = excl;
        cursor[gid] = excl;
    }
    if (b == 0 && t == 0) off[NNODES] = NEDGES;
}

__global__ __launch_bounds__(256) void fill(const int* __restrict__ edges,
                                            int* __restrict__ cursor,
                                            unsigned* __restrict__ buckets)
{
    int e = blockIdx.x * 256 + threadIdx.x;
    if (e >= NEDGES) return;
    int src = edges[e * 3 + 0];
    int rel = edges[e * 3 + 1];
    int dst = edges[e * 3 + 2];
    int pos = atomicAdd(cursor + dst, 1);
    buckets[pos] = (unsigned)src | ((unsigned)rel << 16);
}

// ---------------------------------------------------------------------------
// Stage a [col][k] bf16 128x128 weight into padded LDS (row pitch BP shorts).
static __device__ __forceinline__ void stage_B(const unsigned short* __restrict__ src,
                                               unsigned short* __restrict__ ldsB,
                                               int t)
{
    #pragma unroll
    for (int i = 0; i < 8; ++i) {
        int idx = t + i * 256;          // 2048 x 16B slots
        int col = idx >> 4;
        int slot = idx & 15;
        *(uint4*)(ldsB + (size_t)col * BP + slot * 8) =
            *(const uint4*)(src + (size_t)col * DIM + slot * 8);
    }
}

// ---------------------------------------------------------------------------
// ts_kernel: fused two-phase GEMM. Per 64-row block (4 waves x 16 rows):
//   load A-frags once (f32 -> bf16);
//   phase 1: B=Wn^T in LDS  -> T (bf16) [node blocks] / U (rel blocks)
//   phase 2: B=(I+Ws)^T restaged in the SAME LDS -> Sp (f32, d_out)
// LDS: 34.8KB (B) + 33.8KB (out tile, ushort view for T) = 68.6KB, 2 blk/CU.
// ---------------------------------------------------------------------------
__global__ __launch_bounds__(256) void ts_kernel(
    const float* __restrict__ nodes, const float* __restrict__ rels,
    const unsigned short* __restrict__ btn, const unsigned short* __restrict__ bts,
    unsigned short* __restrict__ T, unsigned short* __restrict__ U,
    float* __restrict__ Sp)
{
    __shared__ __align__(16) unsigned short ldsB[DIM * BP];
    __shared__ __align__(16) float          ldsS[4][16][DIM + SPAD];

    int blk = blockIdx.x;
    bool isRel = blk >= NODE_BLKS;
    const float* A = isRel ? rels : nodes;
    int nrows = isRel ? NRELS : NNODES;
    int rowbase = (isRel ? (blk - NODE_BLKS) : blk) * 64;

    int t  = threadIdx.x;
    int wv = t >> 6;
    int l  = t & 63;
    int r0 = rowbase + wv * 16;
    int m  = l & 15;
    int kg = l >> 4;
    int arow  = r0 + m;
    int arowc = arow < nrows ? arow : nrows - 1;

    // A fragments, loaded/converted ONCE for both phases
    s8f afrag[4];
    #pragma unroll
    for (int ks = 0; ks < 4; ++ks) {
        const float* p = A + (size_t)arowc * DIM + ks * 32 + kg * 8;
        float4 x = *(const float4*)p;
        float4 y = *(const float4*)(p + 4);
        s8f a;
        a[0] = (short)f2bf(x.x); a[1] = (short)f2bf(x.y);
        a[2] = (short)f2bf(x.z); a[3] = (short)f2bf(x.w);
        a[4] = (short)f2bf(y.x); a[5] = (short)f2bf(y.y);
        a[6] = (short)f2bf(y.z); a[7] = (short)f2bf(y.w);
        afrag[ks] = a;
    }

    // ---- phase 1: T/U = A @ Wn ----
    stage_B(btn, ldsB, t);
    __syncthreads();

    unsigned short* ldsT = (unsigned short*)&ldsS[0][0][0];  // ushort view
    const int TP = DIM + TPAD;                               // 136 shorts pitch
    #pragma unroll 2
    for (int ct = 0; ct < 8; ++ct) {
        int col = ct * 16 + m;
        const unsigned short* bp = ldsB + (size_t)col * BP + kg * 8;
        f4 acc = {0.f, 0.f, 0.f, 0.f};
        #pragma unroll
        for (int ks = 0; ks < 4; ++ks)
            acc = __builtin_amdgcn_mfma_f32_16x16x32_bf16(afrag[ks], *(const s8f*)(bp + ks * 32), acc, 0, 0, 0);
        #pragma unroll
        for (int r = 0; r < 4; ++r)
            ldsT[((size_t)wv * 16 + kg * 4 + r) * TP + col] = f2bf(acc[r]);
    }
    __syncthreads();   // ldsT complete; all waves done reading ldsB

    unsigned short* Tout = isRel ? U : T;
    #pragma unroll
    for (int p = 0; p < 4; ++p) {
        int row = p * 4 + kg;
        int rg  = r0 + row;
        if (rg < nrows)
            *(uint4*)(Tout + (size_t)rg * DIM + m * 8) =
                *(const uint4*)&ldsT[((size_t)wv * 16 + row) * TP + m * 8];
    }
    if (isRel) return;   // rel blocks: no self-loop GEMM

    __syncthreads();   // T stores issued; safe to overwrite ldsB and ldsS

    // ---- phase 2: Sp = A @ (I+Ws) ----
    stage_B(bts, ldsB, t);
    __syncthreads();

    #pragma unroll 2
    for (int ct = 0; ct < 8; ++ct) {
        int col = ct * 16 + m;
        const unsigned short* bp = ldsB + (size_t)col * BP + kg * 8;
        f4 acc = {0.f, 0.f, 0.f, 0.f};
        #pragma unroll
        for (int ks = 0; ks < 4; ++ks)
            acc = __builtin_amdgcn_mfma_f32_16x16x32_bf16(afrag[ks], *(const s8f*)(bp + ks * 32), acc, 0, 0, 0);
        #pragma unroll
        for (int r = 0; r < 4; ++r)
            ldsS[wv][kg * 4 + r][col] = acc[r];
    }
    __syncthreads();

    #pragma unroll
    for (int p = 0; p < 4; ++p) {
        int row = p * 4 + kg;
        int rg  = r0 + row;
        if (rg < NNODES) {
            float* orow = Sp + (size_t)rg * DIM;
            #pragma unroll
            for (int j = 0; j < 2; ++j) {
                int c0 = m * 4 + j * 64;
                *(float4*)(orow + c0) = *(const float4*)&ldsS[wv][row][c0];
            }
        }
    }
}

// ---------------------------------------------------------------------------
// gather: full wave per node; halves walk alternate bucket entries (stride 2),
// 4 edges in flight per half. out = Sp[n] + acc/deg (in-place d_out).
// ---------------------------------------------------------------------------
__global__ __launch_bounds__(256) void gather(
    const unsigned short* __restrict__ T, const unsigned short* __restrict__ U,
    const int* __restrict__ off, const unsigned* __restrict__ buckets,
    const float* __restrict__ nodes, const float* __restrict__ wse,
    float* __restrict__ outp)
{
    int tid = blockIdx.x * 256 + threadIdx.x;
    int n = tid >> 6;
    if (n >= NNODES) return;
    int l = threadIdx.x & 63;
    int half = l >> 5;
    int c = l & 31;

    int beg = off[n];
    int end = off[n + 1];

    if (beg == end) {
        // rare (~e^-12 per node): out = h + h @ Wse, straight f32 matvec
        if (half == 0) {
            float s0 = 0, s1 = 0, s2 = 0, s3 = 0;
            for (int k = 0; k < DIM; ++k) {
                float hk = nodes[(size_t)n * DIM + k];
                const float* wr = wse + (size_t)k * DIM + c * 4;
                s0 += hk * wr[0]; s1 += hk * wr[1];
                s2 += hk * wr[2]; s3 += hk * wr[3];
            }
            float4 hv = *(const float4*)(nodes + (size_t)n * DIM + c * 4);
            float4 o = { hv.x + s0, hv.y + s1, hv.z + s2, hv.w + s3 };
            *(float4*)(outp + (size_t)n * DIM + c * 4) = o;
        }
        return;
    }

    float4 acc = make_float4(0.f, 0.f, 0.f, 0.f);
    int i = beg + half;
    // 4 edges in flight per half (8 per wave)
    for (; i + 6 < end; i += 8) {
        unsigned b0 = buckets[i];
        unsigned b1 = buckets[i + 2];
        unsigned b2 = buckets[i + 4];
        unsigned b3 = buckets[i + 6];
        uint2 t0 = *(const uint2*)(T + (size_t)(b0 & 0xFFFFu) * DIM + c * 4);
        uint2 u0 = *(const uint2*)(U + (size_t)(b0 >> 16)     * DIM + c * 4);
        uint2 t1 = *(const uint2*)(T + (size_t)(b1 & 0xFFFFu) * DIM + c * 4);
        uint2 u1 = *(const uint2*)(U + (size_t)(b1 >> 16)     * DIM + c * 4);
        uint2 t2 = *(const uint2*)(T + (size_t)(b2 & 0xFFFFu) * DIM + c * 4);
        uint2 u2 = *(const uint2*)(U + (size_t)(b2 >> 16)     * DIM + c * 4);
        uint2 t3 = *(const uint2*)(T + (size_t)(b3 & 0xFFFFu) * DIM + c * 4);
        uint2 u3 = *(const uint2*)(U + (size_t)(b3 >> 16)     * DIM + c * 4);
        acc.x += bflo(t0.x) + bflo(u0.x); acc.y += bfhi(t0.x) + bfhi(u0.x);
        acc.z += bflo(t0.y) + bflo(u0.y); acc.w += bfhi(t0.y) + bfhi(u0.y);
        acc.x += bflo(t1.x) + bflo(u1.x); acc.y += bfhi(t1.x) + bfhi(u1.x);
        acc.z += bflo(t1.y) + bflo(u1.y); acc.w += bfhi(t1.y) + bfhi(u1.y);
        acc.x += bflo(t2.x) + bflo(u2.x); acc.y += bfhi(t2.x) + bfhi(u2.x);
        acc.z += bflo(t2.y) + bflo(u2.y); acc.w += bfhi(t2.y) + bfhi(u2.y);
        acc.x += bflo(t3.x) + bflo(u3.x); acc.y += bfhi(t3.x) + bfhi(u3.x);
        acc.z += bflo(t3.y) + bflo(u3.y); acc.w += bfhi(t3.y) + bfhi(u3.y);
    }
    for (; i < end; i += 2) {
        unsigned b0 = buckets[i];
        uint2 t0 = *(const uint2*)(T + (size_t)(b0 & 0xFFFFu) * DIM + c * 4);
        uint2 u0 = *(const uint2*)(U + (size_t)(b0 >> 16)     * DIM + c * 4);
        acc.x += bflo(t0.x) + bflo(u0.x); acc.y += bfhi(t0.x) + bfhi(u0.x);
        acc.z += bflo(t0.y) + bflo(u0.y); acc.w += bfhi(t0.y) + bfhi(u0.y);
    }

    acc.x += __shfl_xor(acc.x, 32, 64);
    acc.y += __shfl_xor(acc.y, 32, 64);
    acc.z += __shfl_xor(acc.z, 32, 64);
    acc.w += __shfl_xor(acc.w, 32, 64);

    if (half == 0) {
        float inv = 1.0f / (float)(end - beg);
        float4 sp = *(const float4*)(outp + (size_t)n * DIM + c * 4);
        float4 o = { sp.x + acc.x * inv, sp.y + acc.y * inv,
                     sp.z + acc.z * inv, sp.w + acc.w * inv };
        *(float4*)(outp + (size_t)n * DIM + c * 4) = o;
    }
}

// ---------------------------------------------------------------------------
extern "C" void kernel_launch(void* const* d_in, const int* in_sizes, int n_in,
                              void* d_out, int out_size, void* d_ws, size_t ws_size,
                              hipStream_t stream)
{
    const float* nodes = (const float*)d_in[0];
    const float* rels  = (const float*)d_in[1];
    const int*   edges = (const int*)d_in[2];
    const float* wn    = (const float*)d_in[3];
    const float* wsf   = (const float*)d_in[4];
    const float* wse   = (const float*)d_in[5];
    float* out = (float*)d_out;

    char* ws = (char*)d_ws;
    int*            cnt     = (int*)(ws + OFF_CNT_B);
    int*            off     = (int*)(ws + OFF_OFF_B);
    int*            cursor  = (int*)(ws + OFF_CUR_B);
    int*            bsum    = (int*)(ws + OFF_BSM_B);
    unsigned*       buckets = (unsigned*)(ws + OFF_BKT_B);
    unsigned short* btn     = (unsigned short*)(ws + OFF_BTN_B);
    unsigned short* bts     = (unsigned short*)(ws + OFF_BTS_B);
    unsigned short* T       = (unsigned short*)(ws + OFF_T_B);
    unsigned short* U       = (unsigned short*)(ws + OFF_U_B);

    prep<<<PREP_BLKS, 256, 0, stream>>>(wn, wsf, btn, bts, (int4*)cnt);

    int eb = (NEDGES + 255) / 256;
    hist<<<eb, 256, 0, stream>>>(edges, cnt);
    scan_partial<<<NSB, SCB, 0, stream>>>(cnt, bsum);
    scan_final<<<NSB, SCB, 0, stream>>>(cnt, bsum, off, cursor);
    fill<<<eb, 256, 0, stream>>>(edges, cursor, buckets);

    ts_kernel<<<NODE_BLKS + REL_BLKS, 256, 0, stream>>>(nodes, rels, btn, bts, T, U, out);

    int gb = (NNODES * 64 + 255) / 256;
    gather<<<gb, 256, 0, stream>>>(T, U, off, buckets, nodes, wse, out);
}

// Round 9
// 98.929 us; speedup vs baseline: 1.8073x; 1.3073x over previous
//
#include <hip/hip_runtime.h>

// URGCN layer, MI355X — round 9.
// r8 post-mortem: hist+scan (14us + gaps) exist only to build CSR offsets.
// Replace with fixed-capacity buckets (CAP=48, Poisson(12) tail ~1e-15) +
// guaranteed-correct overflow list drained by the owning gather wave.
// ts_kernel: alias B-stage/T-tile/Sp-tile in ONE 34.8KB LDS buffer -> 4 blk/CU.
//
// Algebra: msg_agg = (Σ_e T[src] + u[rel]) / deg, T = h@Wn (bf16 MFMA),
//          u = rel@Wn.  out = Sp + msg_agg, Sp = h@(I+Wself) (f32, in d_out).

constexpr int NNODES = 50000;
constexpr int NEDGES = 600000;
constexpr int NRELS  = 500;
constexpr int DIM    = 128;
constexpr int CAP    = 48;      // bucket capacity per node
constexpr int OCAP   = 8192;    // overflow list capacity

constexpr int NODE_BLKS = (NNODES + 63) / 64;   // 782
constexpr int REL_BLKS  = (NRELS  + 63) / 64;   // 8

constexpr int BP = 136;   // LDS B row pitch (shorts); 272B -> banks spread
constexpr int TP = 136;   // LDS T tile pitch (shorts)
constexpr int SP = 132;   // LDS S tile pitch (floats)

// prep geometry: zero cnt[50000] + ocount (50004 ints -> 12501 int4)
constexpr int WCONV_BLKS = (DIM * DIM + 255) / 256;            // 64
constexpr int ZERO_INT4S = 12501;
constexpr int ZERO_BLKS  = (ZERO_INT4S + 255) / 256;           // 49
constexpr int PREP_BLKS  = WCONV_BLKS + ZERO_BLKS;             // 113

// ---------------- workspace layout (bytes), ~22.9 MB (ws ~268 MB) ----------
constexpr size_t OFF_CNT_B  = 0;         // int[50000]
constexpr size_t OFF_OCNT_B = 200000;    // int ocount (zeroed with cnt)
constexpr size_t OFF_OBUF_B = 204800;    // uint2[8192]
constexpr size_t OFF_BKT_B  = 270336;    // uint[50000*48] = 9.6 MB
constexpr size_t OFF_BTN_B  = OFF_BKT_B + (size_t)NNODES * CAP * 4;  // Wn^T bf16
constexpr size_t OFF_BTS_B  = OFF_BTN_B + 32768;                     // (I+Ws)^T bf16
constexpr size_t OFF_T_B    = OFF_BTS_B + 32768;                     // ushort[50000*128]
constexpr size_t OFF_U_B    = OFF_T_B + (size_t)NNODES * DIM * 2;    // ushort[500*128]

typedef short s8f __attribute__((ext_vector_type(8)));   // 8 bf16 (4 VGPR)
typedef float f4  __attribute__((ext_vector_type(4)));   // MFMA acc

static __device__ __forceinline__ unsigned short f2bf(float f) {
    unsigned u = __builtin_bit_cast(unsigned, f);
    u += 0x7FFFu + ((u >> 16) & 1u);        // round-to-nearest-even
    return (unsigned short)(u >> 16);
}
static __device__ __forceinline__ float bflo(unsigned v) {
    return __builtin_bit_cast(float, v << 16);
}
static __device__ __forceinline__ float bfhi(unsigned v) {
    return __builtin_bit_cast(float, v & 0xFFFF0000u);
}

// ---------------------------------------------------------------------------
// prep: blocks [0,64) convert weights; blocks [64,113) zero cnt+ocount.
__global__ __launch_bounds__(256) void prep(const float* __restrict__ wn,
                                            const float* __restrict__ wsf,
                                            unsigned short* __restrict__ btn,
                                            unsigned short* __restrict__ bts,
                                            int4* __restrict__ cnt4)
{
    int b = blockIdx.x;
    if (b < WCONV_BLKS) {
        int idx = b * 256 + threadIdx.x;
        int k = idx >> 7, j = idx & 127;
        btn[(size_t)j * DIM + k] = f2bf(wn[idx]);                         // Wn^T
        bts[(size_t)j * DIM + k] = f2bf(wsf[idx] + (k == j ? 1.f : 0.f)); // (I+Ws)^T
    } else {
        int idx = (b - WCONV_BLKS) * 256 + threadIdx.x;
        if (idx < ZERO_INT4S) cnt4[idx] = make_int4(0, 0, 0, 0);
    }
}

// ---------------------------------------------------------------------------
// fill: one pass over edges. pos = cnt[dst]++; slot or overflow list.
__global__ __launch_bounds__(256) void fill(const int* __restrict__ edges,
                                            int* __restrict__ cnt,
                                            unsigned* __restrict__ buckets,
                                            int* __restrict__ ocount,
                                            uint2* __restrict__ obuf)
{
    int e = blockIdx.x * 256 + threadIdx.x;
    if (e >= NEDGES) return;
    int src = edges[e * 3 + 0];
    int rel = edges[e * 3 + 1];
    int dst = edges[e * 3 + 2];
    unsigned packed = (unsigned)src | ((unsigned)rel << 16);
    int pos = atomicAdd(cnt + dst, 1);
    if (pos < CAP) {
        buckets[(size_t)dst * CAP + pos] = packed;
    } else {
        int o = atomicAdd(ocount, 1);
        if (o < OCAP) obuf[o] = make_uint2((unsigned)dst, packed);
    }
}

// ---------------------------------------------------------------------------
// ts_kernel: fused two-phase GEMM, ONE aliased LDS buffer (34.8 KB):
//   [stage Wn^T] -> MFMA T (accs in VGPR) -> [T tile] -> store T
//   [stage (I+Ws)^T] -> MFMA Sp -> [Sp tile] -> store Sp
// 4 blocks/CU (16 waves/CU) vs r8's 2.
// ---------------------------------------------------------------------------
__global__ __launch_bounds__(256, 4) void ts_kernel(
    const float* __restrict__ nodes, const float* __restrict__ rels,
    const unsigned short* __restrict__ btn, const unsigned short* __restrict__ bts,
    unsigned short* __restrict__ T, unsigned short* __restrict__ U,
    float* __restrict__ Sp)
{
    __shared__ __align__(16) char ldsRaw[DIM * BP * 2];   // 34816 B
    unsigned short* ldsB = (unsigned short*)ldsRaw;
    unsigned short* ldsT = (unsigned short*)ldsRaw;       // aliased views
    float*          ldsS = (float*)ldsRaw;

    int blk = blockIdx.x;
    bool isRel = blk >= NODE_BLKS;
    const float* A = isRel ? rels : nodes;
    int nrows = isRel ? NRELS : NNODES;
    int rowbase = (isRel ? (blk - NODE_BLKS) : blk) * 64;

    int t  = threadIdx.x;
    int wv = t >> 6;
    int l  = t & 63;
    int r0 = rowbase + wv * 16;
    int m  = l & 15;
    int kg = l >> 4;
    int arow  = r0 + m;
    int arowc = arow < nrows ? arow : nrows - 1;

    // A fragments, loaded/converted ONCE for both phases
    s8f afrag[4];
    #pragma unroll
    for (int ks = 0; ks < 4; ++ks) {
        const float* p = A + (size_t)arowc * DIM + ks * 32 + kg * 8;
        float4 x = *(const float4*)p;
        float4 y = *(const float4*)(p + 4);
        s8f a;
        a[0] = (short)f2bf(x.x); a[1] = (short)f2bf(x.y);
        a[2] = (short)f2bf(x.z); a[3] = (short)f2bf(x.w);
        a[4] = (short)f2bf(y.x); a[5] = (short)f2bf(y.y);
        a[6] = (short)f2bf(y.z); a[7] = (short)f2bf(y.w);
        afrag[ks] = a;
    }

    // ---- phase 1: T/U = A @ Wn ----
    #pragma unroll
    for (int i = 0; i < 8; ++i) {                  // stage Wn^T
        int idx = t + i * 256;
        int col = idx >> 4, slot = idx & 15;
        *(uint4*)(ldsB + (size_t)col * BP + slot * 8) =
            *(const uint4*)(btn + (size_t)col * DIM + slot * 8);
    }
    __syncthreads();

    f4 acc[8];
    #pragma unroll
    for (int ct = 0; ct < 8; ++ct) {
        int col = ct * 16 + m;
        const unsigned short* bp = ldsB + (size_t)col * BP + kg * 8;
        f4 a = {0.f, 0.f, 0.f, 0.f};
        #pragma unroll
        for (int ks = 0; ks < 4; ++ks)
            a = __builtin_amdgcn_mfma_f32_16x16x32_bf16(afrag[ks], *(const s8f*)(bp + ks * 32), a, 0, 0, 0);
        acc[ct] = a;
    }
    __syncthreads();   // all ldsB reads done; safe to overwrite as ldsT

    #pragma unroll
    for (int ct = 0; ct < 8; ++ct)
        #pragma unroll
        for (int r = 0; r < 4; ++r)
            ldsT[((size_t)wv * 16 + kg * 4 + r) * TP + ct * 16 + m] = f2bf(acc[ct][r]);
    __syncthreads();

    unsigned short* Tout = isRel ? U : T;
    #pragma unroll
    for (int p = 0; p < 4; ++p) {
        int row = p * 4 + kg;
        int rg  = r0 + row;
        if (rg < nrows)
            *(uint4*)(Tout + (size_t)rg * DIM + m * 8) =
                *(const uint4*)&ldsT[((size_t)wv * 16 + row) * TP + m * 8];
    }
    if (isRel) return;   // whole block is rel -> uniform exit

    __syncthreads();   // ldsT reads done; safe to restage

    // ---- phase 2: Sp = A @ (I+Ws) ----
    #pragma unroll
    for (int i = 0; i < 8; ++i) {                  // stage (I+Ws)^T
        int idx = t + i * 256;
        int col = idx >> 4, slot = idx & 15;
        *(uint4*)(ldsB + (size_t)col * BP + slot * 8) =
            *(const uint4*)(bts + (size_t)col * DIM + slot * 8);
    }
    __syncthreads();

    #pragma unroll
    for (int ct = 0; ct < 8; ++ct) {
        int col = ct * 16 + m;
        const unsigned short* bp = ldsB + (size_t)col * BP + kg * 8;
        f4 a = {0.f, 0.f, 0.f, 0.f};
        #pragma unroll
        for (int ks = 0; ks < 4; ++ks)
            a = __builtin_amdgcn_mfma_f32_16x16x32_bf16(afrag[ks], *(const s8f*)(bp + ks * 32), a, 0, 0, 0);
        acc[ct] = a;
    }
    __syncthreads();   // ldsB reads done; overwrite as ldsS

    #pragma unroll
    for (int ct = 0; ct < 8; ++ct)
        #pragma unroll
        for (int r = 0; r < 4; ++r)
            ldsS[((size_t)wv * 16 + kg * 4 + r) * SP + ct * 16 + m] = acc[ct][r];
    __syncthreads();

    #pragma unroll
    for (int p = 0; p < 4; ++p) {
        int row = p * 4 + kg;
        int rg  = r0 + row;
        if (rg < NNODES) {
            float* orow = Sp + (size_t)rg * DIM;
            #pragma unroll
            for (int j = 0; j < 2; ++j) {
                int c0 = m * 4 + j * 64;
                *(float4*)(orow + c0) =
                    *(const float4*)&ldsS[((size_t)wv * 16 + row) * SP + c0];
            }
        }
    }
}

// ---------------------------------------------------------------------------
// gather: full wave per node; halves walk alternate bucket slots, 4 edges in
// flight per half. deg = cnt[n]; slots beyond CAP come from the overflow list
// (scanned only by the rare deg>CAP waves). out = Sp[n] + acc/deg.
// ---------------------------------------------------------------------------
__global__ __launch_bounds__(256) void gather(
    const unsigned short* __restrict__ T, const unsigned short* __restrict__ U,
    const int* __restrict__ cnt, const unsigned* __restrict__ buckets,
    const int* __restrict__ ocount, const uint2* __restrict__ obuf,
    const float* __restrict__ nodes, const float* __restrict__ wse,
    float* __restrict__ outp)
{
    int tid = blockIdx.x * 256 + threadIdx.x;
    int n = tid >> 6;
    if (n >= NNODES) return;
    int l = threadIdx.x & 63;
    int half = l >> 5;
    int c = l & 31;

    int deg = cnt[n];

    if (deg == 0) {
        // rare (~6e-6 per node): out = h + h @ Wse, straight f32 matvec
        if (half == 0) {
            float s0 = 0, s1 = 0, s2 = 0, s3 = 0;
            for (int k = 0; k < DIM; ++k) {
                float hk = nodes[(size_t)n * DIM + k];
                const float* wr = wse + (size_t)k * DIM + c * 4;
                s0 += hk * wr[0]; s1 += hk * wr[1];
                s2 += hk * wr[2]; s3 += hk * wr[3];
            }
            float4 hv = *(const float4*)(nodes + (size_t)n * DIM + c * 4);
            float4 o = { hv.x + s0, hv.y + s1, hv.z + s2, hv.w + s3 };
            *(float4*)(outp + (size_t)n * DIM + c * 4) = o;
        }
        return;
    }

    int beg = n * CAP;
    int end = beg + (deg < CAP ? deg : CAP);

    float4 acc = make_float4(0.f, 0.f, 0.f, 0.f);
    int i = beg + half;
    for (; i + 6 < end; i += 8) {
        unsigned b0 = buckets[i];
        unsigned b1 = buckets[i + 2];
        unsigned b2 = buckets[i + 4];
        unsigned b3 = buckets[i + 6];
        uint2 t0 = *(const uint2*)(T + (size_t)(b0 & 0xFFFFu) * DIM + c * 4);
        uint2 u0 = *(const uint2*)(U + (size_t)(b0 >> 16)     * DIM + c * 4);
        uint2 t1 = *(const uint2*)(T + (size_t)(b1 & 0xFFFFu) * DIM + c * 4);
        uint2 u1 = *(const uint2*)(U + (size_t)(b1 >> 16)     * DIM + c * 4);
        uint2 t2 = *(const uint2*)(T + (size_t)(b2 & 0xFFFFu) * DIM + c * 4);
        uint2 u2 = *(const uint2*)(U + (size_t)(b2 >> 16)     * DIM + c * 4);
        uint2 t3 = *(const uint2*)(T + (size_t)(b3 & 0xFFFFu) * DIM + c * 4);
        uint2 u3 = *(const uint2*)(U + (size_t)(b3 >> 16)     * DIM + c * 4);
        acc.x += bflo(t0.x) + bflo(u0.x); acc.y += bfhi(t0.x) + bfhi(u0.x);
        acc.z += bflo(t0.y) + bflo(u0.y); acc.w += bfhi(t0.y) + bfhi(u0.y);
        acc.x += bflo(t1.x) + bflo(u1.x); acc.y += bfhi(t1.x) + bfhi(u1.x);
        acc.z += bflo(t1.y) + bflo(u1.y); acc.w += bfhi(t1.y) + bfhi(u1.y);
        acc.x += bflo(t2.x) + bflo(u2.x); acc.y += bfhi(t2.x) + bfhi(u2.x);
        acc.z += bflo(t2.y) + bflo(u2.y); acc.w += bfhi(t2.y) + bfhi(u2.y);
        acc.x += bflo(t3.x) + bflo(u3.x); acc.y += bfhi(t3.x) + bfhi(u3.x);
        acc.z += bflo(t3.y) + bflo(u3.y); acc.w += bfhi(t3.y) + bfhi(u3.y);
    }
    for (; i < end; i += 2) {
        unsigned b0 = buckets[i];
        uint2 t0 = *(const uint2*)(T + (size_t)(b0 & 0xFFFFu) * DIM + c * 4);
        uint2 u0 = *(const uint2*)(U + (size_t)(b0 >> 16)     * DIM + c * 4);
        acc.x += bflo(t0.x) + bflo(u0.x); acc.y += bfhi(t0.x) + bfhi(u0.x);
        acc.z += bflo(t0.y) + bflo(u0.y); acc.w += bfhi(t0.y) + bfhi(u0.y);
    }

    if (deg > CAP) {
        // ~never taken; drain the overflow list (parity-split across halves)
        int oc = *ocount;
        if (oc > OCAP) oc = OCAP;
        for (int j = 0; j < oc; ++j) {
            uint2 e = obuf[j];
            if ((int)e.x == n && (j & 1) == half) {
                unsigned b0 = e.y;
                uint2 t0 = *(const uint2*)(T + (size_t)(b0 & 0xFFFFu) * DIM + c * 4);
                uint2 u0 = *(const uint2*)(U + (size_t)(b0 >> 16)     * DIM + c * 4);
                acc.x += bflo(t0.x) + bflo(u0.x); acc.y += bfhi(t0.x) + bfhi(u0.x);
                acc.z += bflo(t0.y) + bflo(u0.y); acc.w += bfhi(t0.y) + bfhi(u0.y);
            }
        }
    }

    acc.x += __shfl_xor(acc.x, 32, 64);
    acc.y += __shfl_xor(acc.y, 32, 64);
    acc.z += __shfl_xor(acc.z, 32, 64);
    acc.w += __shfl_xor(acc.w, 32, 64);

    if (half == 0) {
        float inv = 1.0f / (float)deg;
        float4 sp = *(const float4*)(outp + (size_t)n * DIM + c * 4);
        float4 o = { sp.x + acc.x * inv, sp.y + acc.y * inv,
                     sp.z + acc.z * inv, sp.w + acc.w * inv };
        *(float4*)(outp + (size_t)n * DIM + c * 4) = o;
    }
}

// ---------------------------------------------------------------------------
extern "C" void kernel_launch(void* const* d_in, const int* in_sizes, int n_in,
                              void* d_out, int out_size, void* d_ws, size_t ws_size,
                              hipStream_t stream)
{
    const float* nodes = (const float*)d_in[0];
    const float* rels  = (const float*)d_in[1];
    const int*   edges = (const int*)d_in[2];
    const float* wn    = (const float*)d_in[3];
    const float* wsf   = (const float*)d_in[4];
    const float* wse   = (const float*)d_in[5];
    float* out = (float*)d_out;

    char* ws = (char*)d_ws;
    int*            cnt     = (int*)(ws + OFF_CNT_B);
    int*            ocount  = (int*)(ws + OFF_OCNT_B);
    uint2*          obuf    = (uint2*)(ws + OFF_OBUF_B);
    unsigned*       buckets = (unsigned*)(ws + OFF_BKT_B);
    unsigned short* btn     = (unsigned short*)(ws + OFF_BTN_B);
    unsigned short* bts     = (unsigned short*)(ws + OFF_BTS_B);
    unsigned short* T       = (unsigned short*)(ws + OFF_T_B);
    unsigned short* U       = (unsigned short*)(ws + OFF_U_B);

    prep<<<PREP_BLKS, 256, 0, stream>>>(wn, wsf, btn, bts, (int4*)cnt);

    int eb = (NEDGES + 255) / 256;
    fill<<<eb, 256, 0, stream>>>(edges, cnt, buckets, ocount, obuf);

    ts_kernel<<<NODE_BLKS + REL_BLKS, 256, 0, stream>>>(nodes, rels, btn, bts, T, U, out);

    int gb = (NNODES * 64 + 255) / 256;
    gather<<<gb, 256, 0, stream>>>(T, U, cnt, buckets, ocount, obuf, nodes, wse, out);
}